// Round 9
// baseline (588.117 us; speedup 1.0000x reference)
//
#include <hip/hip_runtime.h>
#include <stdint.h>

// MGMCGCN — 3x (binary-GCN + 5-step LSTM + fc/tanh).
// Dtypes: float inputs f32, adj int32, ALL OUTPUTS f32. Internal bf16 MFMA.
// N=4096, F=H=256, K=3, T=5, G=4H=1024.
// R9 change log:
//  - REVERT R8 cooperative fusion (grid.sync cross-XCD visibility produced
//    wrong results; strike two for cooperative — kernel boundaries are the
//    reliable device-scope fence). Base = R6-verified bodies (572.6 us).
//  - NEW (only delta): nontemporal load/store for the 402 MB adj->adj_out
//    stream in adjxw (read-once / write-once, never re-read) — keeps L2/L3
//    clean for abits/uT/weights that downstream kernels re-read.
#define NN_ 4096
#define FD 256
#define HD 256
#define KC 3
#define GD 1024
#define SA 40      // padded LDS pitch (shorts) for fused-xw staging
#define BPITCH 144 // bitsA LDS row pitch (bytes)

typedef __attribute__((ext_vector_type(4))) unsigned int vu4;     // 16 B
typedef __attribute__((ext_vector_type(4))) int vi4;              // 16 B
typedef __attribute__((ext_vector_type(4))) float vf4;            // 16 B
typedef __attribute__((ext_vector_type(4))) unsigned short vus4;  // 8 B
typedef __attribute__((ext_vector_type(8))) short short8;         // bf16x8 MFMA frag
typedef __attribute__((ext_vector_type(4))) float f32x4;          // MFMA acc

typedef __attribute__((address_space(1))) const void GV;
typedef __attribute__((address_space(3))) void LV;
__device__ __forceinline__ void gl16(const void* g, void* l) {
    __builtin_amdgcn_global_load_lds((GV*)g, (LV*)l, 16, 0, 0);
}

__device__ __forceinline__ float b2f(unsigned short u) {
    unsigned int v = ((unsigned int)u) << 16; float f; __builtin_memcpy(&f, &v, 4); return f;
}
__device__ __forceinline__ unsigned short f2b(float x) {
    unsigned int u; __builtin_memcpy(&u, &x, 4);
    u = (u + 0x7FFFu + ((u >> 16) & 1u)) >> 16;   // RNE
    return (unsigned short)u;
}
__device__ __forceinline__ void cvt8(const float* __restrict__ g, unsigned short* o) {
    vf4 a = *(const vf4*)g, b = *(const vf4*)(g + 4);
    o[0] = f2b(a[0]); o[1] = f2b(a[1]); o[2] = f2b(a[2]); o[3] = f2b(a[3]);
    o[4] = f2b(b[0]); o[5] = f2b(b[1]); o[6] = f2b(b[2]); o[7] = f2b(b[3]);
}
// fast transcendentals: v_rcp_f32-based; correct saturation at +/-inf.
__device__ __forceinline__ float frcp(float x) { return __builtin_amdgcn_rcpf(x); }
__device__ __forceinline__ float sigm(float v) { return frcp(1.f + __expf(-v)); }
__device__ __forceinline__ float ftanh(float v) { return 1.f - 2.f * frcp(__expf(2.f * v) + 1.f); }

// ---------------------------------------------------------------------------
// adjxw: blocks 0..4095 = adj pass (adj->f32 copy, bit planes, dinv f32+bf16;
// blocks <864 also convert [wih|whh|fcw]->wb). Blocks 4096..4863 = gemm_xw
// (UNSCALED u = x@gnn_w, transposed store uT[k][h][j]).
// adj stream uses nontemporal load/store (read-once / write-once).
// ---------------------------------------------------------------------------
__global__ __launch_bounds__(256) void adjxw(const int* __restrict__ adj,
        float* __restrict__ adj_out, unsigned char* __restrict__ abits,
        float* __restrict__ dinv, unsigned short* __restrict__ dinvb,
        const float* __restrict__ wih, const float* __restrict__ whh,
        const float* __restrict__ fcw, unsigned short* __restrict__ wb,
        const float* __restrict__ gnnw, const float* __restrict__ x,
        unsigned short* __restrict__ uT) {
    const int bid = blockIdx.x, t = threadIdx.x;
    __shared__ __align__(16) unsigned short sA[64 * SA], sB[64 * SA];  // xw branch
    __shared__ unsigned char nib[3][1024];                              // adj branch
    __shared__ float r0[256], r1[256], r2[256];
    if (bid >= 4096) {
        // ---------------- fused gemm_xw (unscaled) ----------------
        const int b2 = bid - 4096;
        const int k = b2 >> 8, rem = b2 & 255, bn = rem >> 2, bg = rem & 3;
        const int lane = t & 63, wave = t >> 6;
        const int m = lane & 15, q = lane >> 4, ko = q * 8;
        const int h0 = bg * 64;
        f32x4 acc[4] = {};
        const float* A0 = x + (size_t)(bn * 64) * FD;
        const float* B0 = gnnw + (size_t)k * FD * HD;
        const int r = t >> 2, c8 = (t & 3) << 3;
        const int fB = t >> 3, c8B = (t & 7) << 3;
        for (int k0 = 0; k0 < FD; k0 += 32) {
            alignas(16) unsigned short tA[8], tB[8];
            cvt8(A0 + (size_t)r * FD + k0 + c8, tA);
            *(vu4*)(sA + r * SA + c8) = *(vu4*)tA;
            cvt8(B0 + (size_t)(k0 + fB) * HD + h0 + c8B, tB);
#pragma unroll
            for (int e = 0; e < 8; ++e) sB[(c8B + e) * SA + fB] = tB[e];
            __syncthreads();
            short8 af = *(const short8*)(sA + (wave * 16 + m) * SA + ko);
#pragma unroll
            for (int ct = 0; ct < 4; ++ct) {
                short8 bf = *(const short8*)(sB + (ct * 16 + m) * SA + ko);
                acc[ct] = __builtin_amdgcn_mfma_f32_16x16x32_bf16(af, bf, acc[ct], 0, 0, 0);
            }
            __syncthreads();
        }
        unsigned short* uTk = uT + (size_t)k * HD * NN_;
#pragma unroll
        for (int ct = 0; ct < 4; ++ct)
#pragma unroll
            for (int r2 = 0; r2 < 4; ++r2) {
                int col = h0 + ct * 16 + m;
                int row = bn * 64 + wave * 16 + q * 4 + r2;
                uTk[(size_t)col * NN_ + row] = f2b(acc[ct][r2]);
            }
        return;
    }
    // ---------------- adj pass ----------------
    const int i = bid;
    if (i < 864) {   // one-time weight conversion: wih|whh|fcw (exactly 864*2048)
        size_t e = ((size_t)i * 256 + t) * 8;
        const float* src; size_t off;
        if (e < 786432)       { src = wih; off = e; }
        else if (e < 1572864) { src = whh; off = e - 786432; }
        else                  { src = fcw; off = e - 1572864; }
        alignas(16) unsigned short o[8];
        cvt8(src + off, o);
        *(vu4*)(wb + e) = *(vu4*)o;
    }
    const int* src = adj + (size_t)i * 12288;
    float* dstf = adj_out + (size_t)i * 12288;
    float s0 = 0.f, s1 = 0.f, s2 = 0.f;
#pragma unroll
    for (int it = 0; it < 4; ++it) {
        int p = it * 256 + t;
        int jq = p * 4;
        vi4 a = __builtin_nontemporal_load((const vi4*)(src + jq * 3));
        vi4 b = __builtin_nontemporal_load((const vi4*)(src + jq * 3 + 4));
        vi4 c = __builtin_nontemporal_load((const vi4*)(src + jq * 3 + 8));
        int vv[12] = {a[0],a[1],a[2],a[3],b[0],b[1],b[2],b[3],c[0],c[1],c[2],c[3]};
        float ff[12];
#pragma unroll
        for (int e = 0; e < 12; ++e) ff[e] = vv[e] ? 1.f : 0.f;
        vf4 w0 = {ff[0],ff[1],ff[2],ff[3]}, w1 = {ff[4],ff[5],ff[6],ff[7]}, w2 = {ff[8],ff[9],ff[10],ff[11]};
        __builtin_nontemporal_store(w0, (vf4*)(dstf + jq * 3));
        __builtin_nontemporal_store(w1, (vf4*)(dstf + jq * 3 + 4));
        __builtin_nontemporal_store(w2, (vf4*)(dstf + jq * 3 + 8));
#pragma unroll
        for (int k = 0; k < 3; ++k) {
            unsigned int nb = (vv[k] ? 1u : 0u) | (vv[3 + k] ? 2u : 0u)
                            | (vv[6 + k] ? 4u : 0u) | (vv[9 + k] ? 8u : 0u);
            nib[k][p] = (unsigned char)nb;
        }
        s0 += ff[0] + ff[3] + ff[6] + ff[9];
        s1 += ff[1] + ff[4] + ff[7] + ff[10];
        s2 += ff[2] + ff[5] + ff[8] + ff[11];
    }
    r0[t] = s0; r1[t] = s1; r2[t] = s2;
    __syncthreads();
#pragma unroll
    for (int k = 0; k < 3; ++k) {
        unsigned int b0 = (unsigned int)nib[k][t * 4 + 0] | ((unsigned int)nib[k][t * 4 + 1] << 4);
        unsigned int b1 = (unsigned int)nib[k][t * 4 + 2] | ((unsigned int)nib[k][t * 4 + 3] << 4);
        *(unsigned short*)(abits + ((size_t)k * NN_ + i) * 512 + t * 2) =
            (unsigned short)(b0 | (b1 << 8));
    }
    for (int off = 128; off > 0; off >>= 1) {
        if (t < off) { r0[t] += r0[t + off]; r1[t] += r1[t + off]; r2[t] += r2[t + off]; }
        __syncthreads();
    }
    if (t == 0) {
        float d0 = 1.f / sqrtf(1.f + r0[0]);
        float d1 = 1.f / sqrtf(1.f + r1[0]);
        float d2 = 1.f / sqrtf(1.f + r2[0]);
        dinv[i]           = d0; dinvb[i]            = f2b(d0);
        dinv[NN_ + i]     = d1; dinvb[NN_ + i]      = f2b(d1);
        dinv[2 * NN_ + i] = d2; dinvb[2 * NN_ + i]  = f2b(d2);
    }
}

// ---------------------------------------------------------------------------
// gemm_agg v7: 128x128 tiles, 2x2 waves, j-split s=4 (grid 768, XCD swizzle).
// K-step 64 via two 32-j half-buffers (sB0/sB1, 64B pitch each) -> one
// barrier pair per 32 MFMA. A expanded from bit-plane to bf16(dinv_j).
// ---------------------------------------------------------------------------
__global__ __launch_bounds__(256) void gemm_agg(const unsigned char* __restrict__ abits,
        const unsigned short* __restrict__ uT, const unsigned short* __restrict__ dinvb,
        const float* __restrict__ dinv, unsigned short* __restrict__ pbuf) {
    __shared__ __align__(16) unsigned char bitsA[128 * BPITCH];    // 18 KB
    __shared__ __align__(16) unsigned short sB0[128 * 32];          // 8 KB (j half 0)
    __shared__ __align__(16) unsigned short sB1[128 * 32];          // 8 KB (j half 1)
    __shared__ __align__(16) unsigned short sDv[1024];              // 2 KB dinv slice
    const int d = blockIdx.x;                  // 0..767
    const int w = (d & 7) * 96 + (d >> 3);     // bijective XCD-chunked remap
    const int bh = w & 1, bi = (w >> 1) & 31, z = w >> 6;
    const int k = z >> 2, s = z & 3;
    const int t = threadIdx.x, lane = t & 63, wave = t >> 6;
    const int wi = wave & 1, wh = wave >> 1;
    const int m = lane & 15, q = lane >> 4, ko = q * 8;
    const int i0 = bi * 128, h0 = bh * 128, jbase = s * 1024;
    {   // stage the A bit-tile once: 128 rows x 128 B
        const int row = t >> 1, half = t & 1;
        const unsigned char* bsrc = abits + ((size_t)k * NN_ + i0 + row) * 512 + s * 128 + half * 64;
        unsigned char* bdst = bitsA + row * BPITCH + half * 64;
        vu4 v0 = *(const vu4*)(bsrc);
        vu4 v1 = *(const vu4*)(bsrc + 16);
        vu4 v2 = *(const vu4*)(bsrc + 32);
        vu4 v3 = *(const vu4*)(bsrc + 48);
        *(vu4*)(bdst)      = v0;
        *(vu4*)(bdst + 16) = v1;
        *(vu4*)(bdst + 32) = v2;
        *(vu4*)(bdst + 48) = v3;
    }
    if (t < 128)   // stage the dinv_j slice for this j-chunk (1024 bf16)
        *(vu4*)(sDv + t * 8) = *(const vu4*)(dinvb + (size_t)k * NN_ + jbase + t * 8);
    f32x4 acc[4][4] = {};
    const int lrow = lane >> 2, lcol = (lane & 3) << 3;
    const unsigned short* Bg0 = uT + ((size_t)(k * 256 + h0 + wave * 32 + lrow)) * NN_ + jbase + lcol;
    const unsigned short* Bg1 = Bg0 + (size_t)16 * NN_;
    unsigned short* lB00 = sB0 + (wave * 32) * 32;
    unsigned short* lB01 = lB00 + 16 * 32;
    unsigned short* lB10 = sB1 + (wave * 32) * 32;
    unsigned short* lB11 = lB10 + 16 * 32;
    const int arowb = (wi * 64 + m) * BPITCH + q;
    for (int j0 = 0; j0 < 1024; j0 += 64) {
        gl16(Bg0 + j0, lB00);
        gl16(Bg1 + j0, lB01);
        gl16(Bg0 + j0 + 32, lB10);
        gl16(Bg1 + j0 + 32, lB11);
        __syncthreads();
        const int jby = j0 >> 3;
        short8 dv0 = *(const short8*)(sDv + j0 + ko);
        short8 dv1 = *(const short8*)(sDv + j0 + 32 + ko);
        short8 af0[4], af1[4];
#pragma unroll
        for (int rt = 0; rt < 4; ++rt) {
            unsigned int by0 = bitsA[arowb + rt * 16 * BPITCH + jby];
            unsigned int by1 = bitsA[arowb + rt * 16 * BPITCH + jby + 4];
#pragma unroll
            for (int e = 0; e < 8; ++e) {
                af0[rt][e] = (short)(((by0 >> e) & 1u) ? dv0[e] : (short)0);
                af1[rt][e] = (short)(((by1 >> e) & 1u) ? dv1[e] : (short)0);
            }
        }
#pragma unroll
        for (int ct = 0; ct < 4; ++ct) {
            short8 bf0 = *(const short8*)(sB0 + (wh * 64 + ct * 16 + m) * 32 + ko);
#pragma unroll
            for (int rt = 0; rt < 4; ++rt)
                acc[rt][ct] = __builtin_amdgcn_mfma_f32_16x16x32_bf16(af0[rt], bf0, acc[rt][ct], 0, 0, 0);
        }
#pragma unroll
        for (int ct = 0; ct < 4; ++ct) {
            short8 bf1 = *(const short8*)(sB1 + (wh * 64 + ct * 16 + m) * 32 + ko);
#pragma unroll
            for (int rt = 0; rt < 4; ++rt)
                acc[rt][ct] = __builtin_amdgcn_mfma_f32_16x16x32_bf16(af1[rt], bf1, acc[rt][ct], 0, 0, 0);
        }
        __syncthreads();
    }
    const int addself = ((bi >> 3) == s);
#pragma unroll
    for (int rt = 0; rt < 4; ++rt)
#pragma unroll
        for (int ct = 0; ct < 4; ++ct)
#pragma unroll
            for (int r2 = 0; r2 < 4; ++r2) {
                int row = i0 + wi * 64 + rt * 16 + q * 4 + r2;
                int col = h0 + wh * 64 + ct * 16 + m;
                float v = acc[rt][ct][r2];
                if (addself)
                    v += dinv[(size_t)k * NN_ + row]
                       * b2f(uT[((size_t)k * 256 + col) * NN_ + row]);
                pbuf[(((size_t)s * 3 + k) * NN_ + row) * 256 + col] = f2b(v);
            }
}

// ---------------------------------------------------------------------------
// agg_reduce: xt[k][i][h] = f2b(dinv[k][i] * (sum_s pbuf[s]) + gnnb[k][h])
// ---------------------------------------------------------------------------
__global__ __launch_bounds__(256) void agg_reduce(const unsigned short* __restrict__ pbuf,
        const float* __restrict__ dinv, const float* __restrict__ gnnb,
        unsigned short* __restrict__ xt) {
    size_t e8 = ((size_t)blockIdx.x * 256 + threadIdx.x) * 8;
    int k = (int)(e8 >> 20);
    int i = (int)((e8 >> 8) & 4095);
    int h = (int)(e8 & 255);
    float di = dinv[k * NN_ + i];
    const size_t KIH = (size_t)KC * NN_ * HD;
    alignas(16) unsigned short p0[8], p1[8], p2[8], p3[8], o[8];
    *(vu4*)p0 = *(const vu4*)(pbuf + 0 * KIH + e8);
    *(vu4*)p1 = *(const vu4*)(pbuf + 1 * KIH + e8);
    *(vu4*)p2 = *(const vu4*)(pbuf + 2 * KIH + e8);
    *(vu4*)p3 = *(const vu4*)(pbuf + 3 * KIH + e8);
#pragma unroll
    for (int e = 0; e < 8; ++e) {
        float v = b2f(p0[e]) + b2f(p1[e]) + b2f(p2[e]) + b2f(p3[e]);
        o[e] = f2b(di * v + gnnb[k * HD + h + e]);
    }
    *(vu4*)(xt + e8) = *(vu4*)o;
}

// ---------------------------------------------------------------------------
// lstm_gate (t=0): NT GEMM xt @ wih^T via gl16 (K-step 64, half-buffers);
// +bih+bhh -> gX2; fused t=0 cell. Grid 768, XCD swizzle.
// ---------------------------------------------------------------------------
__global__ __launch_bounds__(256) void lstm_gate(const unsigned short* __restrict__ A,
        const unsigned short* __restrict__ W, const float* __restrict__ b1,
        const float* __restrict__ b2, unsigned short* __restrict__ gX2,
        float* __restrict__ cbuf, unsigned short* __restrict__ hbuf) {
    __shared__ __align__(16) unsigned short sA0[128 * 32], sA1[128 * 32];   // 16 KB
    __shared__ __align__(16) unsigned short sB0[128 * 32], sB1[128 * 32];   // 16 KB
    const int d = blockIdx.x;
    const int w = (d & 7) * 96 + (d >> 3);
    const int chb = w & 7, bn = w >> 3;
    const int t = threadIdx.x, lane = t & 63, wave = t >> 6;
    const int m = lane & 15, q = lane >> 4, ko = q * 8;
    const int kk = bn >> 5;
    f32x4 acc[2][2][4] = {};
    const int lrow = lane >> 2, lcol = (lane & 3) << 3;
    const unsigned short* A0 = A + (size_t)bn * 128 * 256;
    const unsigned short* W0 = W + (size_t)kk * GD * 256 + (size_t)chb * 32 * 256;
    const unsigned short* Ag0 = A0 + (size_t)(wave * 32 + lrow) * 256 + lcol;
    const unsigned short* Ag1 = Ag0 + 16 * 256;
    const unsigned short* Bg0 = W0 + (size_t)(wave * 256 + lrow) * 256 + lcol;
    const unsigned short* Bg1 = Bg0 + 16 * 256;
    unsigned short* lA00 = sA0 + (wave * 32) * 32; unsigned short* lA01 = lA00 + 16 * 32;
    unsigned short* lA10 = sA1 + (wave * 32) * 32; unsigned short* lA11 = lA10 + 16 * 32;
    unsigned short* lB00 = sB0 + (wave * 32) * 32; unsigned short* lB01 = lB00 + 16 * 32;
    unsigned short* lB10 = sB1 + (wave * 32) * 32; unsigned short* lB11 = lB10 + 16 * 32;
    for (int k0 = 0; k0 < 256; k0 += 64) {
        gl16(Ag0 + k0, lA00);      gl16(Ag1 + k0, lA01);
        gl16(Ag0 + k0 + 32, lA10); gl16(Ag1 + k0 + 32, lA11);
        gl16(Bg0 + k0, lB00);      gl16(Bg1 + k0, lB01);
        gl16(Bg0 + k0 + 32, lB10); gl16(Bg1 + k0 + 32, lB11);
        __syncthreads();
        short8 af0[2], af1[2];
#pragma unroll
        for (int rt = 0; rt < 2; ++rt) {
            af0[rt] = *(const short8*)(sA0 + (wave * 32 + rt * 16 + m) * 32 + ko);
            af1[rt] = *(const short8*)(sA1 + (wave * 32 + rt * 16 + m) * 32 + ko);
        }
#pragma unroll
        for (int g = 0; g < 4; ++g)
#pragma unroll
            for (int cc = 0; cc < 2; ++cc) {
                short8 bf0 = *(const short8*)(sB0 + (g * 32 + cc * 16 + m) * 32 + ko);
#pragma unroll
                for (int rt = 0; rt < 2; ++rt)
                    acc[rt][cc][g] = __builtin_amdgcn_mfma_f32_16x16x32_bf16(af0[rt], bf0, acc[rt][cc][g], 0, 0, 0);
                short8 bf1 = *(const short8*)(sB1 + (g * 32 + cc * 16 + m) * 32 + ko);
#pragma unroll
                for (int rt = 0; rt < 2; ++rt)
                    acc[rt][cc][g] = __builtin_amdgcn_mfma_f32_16x16x32_bf16(af1[rt], bf1, acc[rt][cc][g], 0, 0, 0);
            }
        __syncthreads();
    }
#pragma unroll
    for (int rt = 0; rt < 2; ++rt)
#pragma unroll
        for (int cc = 0; cc < 2; ++cc)
#pragma unroll
            for (int r2 = 0; r2 < 4; ++r2) {
                int row = bn * 128 + wave * 32 + rt * 16 + q * 4 + r2;
                int ch = chb * 32 + cc * 16 + m;
                size_t goff = ((size_t)row * 256 + ch) * 4;
                size_t coff = (size_t)row * 256 + ch;
                float v[4];
                vus4 o;
#pragma unroll
                for (int g = 0; g < 4; ++g) {
                    v[g] = acc[rt][cc][g][r2]
                         + b1[kk * GD + g * 256 + ch] + b2[kk * GD + g * 256 + ch];
                    o[g] = f2b(v[g]);
                }
                *(vus4*)(gX2 + goff) = o;
                float cn = sigm(v[0]) * ftanh(v[2]);
                cbuf[coff] = cn;
                hbuf[coff] = f2b(sigm(v[3]) * ftanh(cn));
            }
}

// ---------------------------------------------------------------------------
// lstm_step: NT GEMM h_prev @ whh^T (K-step 64, half-buffers); g = v + gX2;
// cell update with cbuf (f32); write c, h_next (ping-pong, no race).
// ---------------------------------------------------------------------------
__global__ __launch_bounds__(256) void lstm_step(const unsigned short* __restrict__ A,
        const unsigned short* __restrict__ W, const unsigned short* __restrict__ gX2,
        float* __restrict__ cbuf, unsigned short* __restrict__ hbuf) {
    __shared__ __align__(16) unsigned short sA0[128 * 32], sA1[128 * 32];   // 16 KB
    __shared__ __align__(16) unsigned short sB0[128 * 32], sB1[128 * 32];   // 16 KB
    const int d = blockIdx.x;
    const int w = (d & 7) * 96 + (d >> 3);
    const int chb = w & 7, bn = w >> 3;
    const int t = threadIdx.x, lane = t & 63, wave = t >> 6;
    const int m = lane & 15, q = lane >> 4, ko = q * 8;
    const int kk = bn >> 5;
    f32x4 acc[2][2][4] = {};
    const int lrow = lane >> 2, lcol = (lane & 3) << 3;
    const unsigned short* A0 = A + (size_t)bn * 128 * 256;
    const unsigned short* W0 = W + (size_t)kk * GD * 256 + (size_t)chb * 32 * 256;
    const unsigned short* Ag0 = A0 + (size_t)(wave * 32 + lrow) * 256 + lcol;
    const unsigned short* Ag1 = Ag0 + 16 * 256;
    const unsigned short* Bg0 = W0 + (size_t)(wave * 256 + lrow) * 256 + lcol;
    const unsigned short* Bg1 = Bg0 + 16 * 256;
    unsigned short* lA00 = sA0 + (wave * 32) * 32; unsigned short* lA01 = lA00 + 16 * 32;
    unsigned short* lA10 = sA1 + (wave * 32) * 32; unsigned short* lA11 = lA10 + 16 * 32;
    unsigned short* lB00 = sB0 + (wave * 32) * 32; unsigned short* lB01 = lB00 + 16 * 32;
    unsigned short* lB10 = sB1 + (wave * 32) * 32; unsigned short* lB11 = lB10 + 16 * 32;
    for (int k0 = 0; k0 < 256; k0 += 64) {
        gl16(Ag0 + k0, lA00);      gl16(Ag1 + k0, lA01);
        gl16(Ag0 + k0 + 32, lA10); gl16(Ag1 + k0 + 32, lA11);
        gl16(Bg0 + k0, lB00);      gl16(Bg1 + k0, lB01);
        gl16(Bg0 + k0 + 32, lB10); gl16(Bg1 + k0 + 32, lB11);
        __syncthreads();
        short8 af0[2], af1[2];
#pragma unroll
        for (int rt = 0; rt < 2; ++rt) {
            af0[rt] = *(const short8*)(sA0 + (wave * 32 + rt * 16 + m) * 32 + ko);
            af1[rt] = *(const short8*)(sA1 + (wave * 32 + rt * 16 + m) * 32 + ko);
        }
#pragma unroll
        for (int g = 0; g < 4; ++g)
#pragma unroll
            for (int cc = 0; cc < 2; ++cc) {
                short8 bf0 = *(const short8*)(sB0 + (g * 32 + cc * 16 + m) * 32 + ko);
#pragma unroll
                for (int rt = 0; rt < 2; ++rt)
                    acc[rt][cc][g] = __builtin_amdgcn_mfma_f32_16x16x32_bf16(af0[rt], bf0, acc[rt][cc][g], 0, 0, 0);
                short8 bf1 = *(const short8*)(sB1 + (g * 32 + cc * 16 + m) * 32 + ko);
#pragma unroll
                for (int rt = 0; rt < 2; ++rt)
                    acc[rt][cc][g] = __builtin_amdgcn_mfma_f32_16x16x32_bf16(af1[rt], bf1, acc[rt][cc][g], 0, 0, 0);
            }
        __syncthreads();
    }
#pragma unroll
    for (int rt = 0; rt < 2; ++rt)
#pragma unroll
        for (int cc = 0; cc < 2; ++cc)
#pragma unroll
            for (int r2 = 0; r2 < 4; ++r2) {
                int row = bn * 128 + wave * 32 + rt * 16 + q * 4 + r2;
                int ch = chb * 32 + cc * 16 + m;
                size_t goff = ((size_t)row * 256 + ch) * 4;
                size_t coff = (size_t)row * 256 + ch;
                vus4 gv = *(const vus4*)(gX2 + goff);
                float iv = acc[rt][cc][0][r2] + b2f(gv[0]);
                float fv = acc[rt][cc][1][r2] + b2f(gv[1]);
                float gg = acc[rt][cc][2][r2] + b2f(gv[2]);
                float ov = acc[rt][cc][3][r2] + b2f(gv[3]);
                float cn = sigm(fv) * cbuf[coff] + sigm(iv) * ftanh(gg);
                cbuf[coff] = cn;
                hbuf[coff] = f2b(sigm(ov) * ftanh(cn));
            }
}

// ---------------------------------------------------------------------------
// fc_final: one block computes 64x64 output for ALL 3 k (acc[3][4]), then the
// final epilogue inline: delta_k = tanh(h@fcw^T + fcb); pred/res from x+delta.
// ---------------------------------------------------------------------------
__global__ __launch_bounds__(256) void fc_final(const unsigned short* __restrict__ A,
        const unsigned short* __restrict__ W, const float* __restrict__ fcb,
        const float* __restrict__ x, float* __restrict__ pred, float* __restrict__ res) {
    __shared__ __align__(16) unsigned short sA[3][64 * 32], sB[3][64 * 32];  // 24 KB
    const int bg = blockIdx.x, bn = blockIdx.y;
    const int t = threadIdx.x, lane = t & 63, wave = t >> 6;
    const int m = lane & 15, q = lane >> 4, ko = q * 8;
    f32x4 acc[3][4] = {};
    const int lrow = lane >> 2, lcol = (lane & 3) << 3;
    const unsigned short* Ag[3]; const unsigned short* Bg[3];
#pragma unroll
    for (int k = 0; k < 3; ++k) {
        Ag[k] = A + ((size_t)k * NN_ + bn * 64 + wave * 16 + lrow) * HD + lcol;
        Bg[k] = W + ((size_t)k * FD + bg * 64 + wave * 16 + lrow) * HD + lcol;
    }
    for (int k0 = 0; k0 < HD; k0 += 32) {
#pragma unroll
        for (int k = 0; k < 3; ++k) {
            gl16(Ag[k] + k0, sA[k] + (wave * 16) * 32);
            gl16(Bg[k] + k0, sB[k] + (wave * 16) * 32);
        }
        __syncthreads();
#pragma unroll
        for (int k = 0; k < 3; ++k) {
            short8 af = *(const short8*)(sA[k] + (wave * 16 + m) * 32 + ko);
#pragma unroll
            for (int ct = 0; ct < 4; ++ct) {
                short8 bf = *(const short8*)(sB[k] + (ct * 16 + m) * 32 + ko);
                acc[k][ct] = __builtin_amdgcn_mfma_f32_16x16x32_bf16(af, bf, acc[k][ct], 0, 0, 0);
            }
        }
        __syncthreads();
    }
#pragma unroll
    for (int ct = 0; ct < 4; ++ct)
#pragma unroll
        for (int r2 = 0; r2 < 4; ++r2) {
            int col = bg * 64 + ct * 16 + m;
            int row = bn * 64 + wave * 16 + q * 4 + r2;
            float d0 = ftanh(acc[0][ct][r2] + fcb[col]);
            float d1 = ftanh(acc[1][ct][r2] + fcb[FD + col]);
            float d2 = ftanh(acc[2][ct][r2] + fcb[2 * FD + col]);
            float xf = x[(size_t)row * FD + col];
            bool sg = (col >= 10) && (col < 253);
            float dm = (d0 + d1 + d2) * (1.f / 3.f);
            float p = xf + dm; if (sg) p = sigm(p);
            pred[(size_t)row * FD + col] = p;
            float z0 = xf + d0; if (sg) z0 = sigm(z0);
            float z1 = xf + d1; if (sg) z1 = sigm(z1);
            float z2 = xf + d2; if (sg) z2 = sigm(z2);
            size_t rb = ((size_t)row * FD + col) * 3;
            res[rb] = z0; res[rb + 1] = z1; res[rb + 2] = z2;
        }
}

extern "C" void kernel_launch(void* const* d_in, const int* in_sizes, int n_in,
                              void* d_out, int out_size, void* d_ws, size_t ws_size,
                              hipStream_t stream) {
    const float* x    = (const float*)d_in[0];
    const float* gnnw = (const float*)d_in[1];
    const float* gnnb = (const float*)d_in[2];
    const float* wih  = (const float*)d_in[3];
    const float* whh  = (const float*)d_in[4];
    const float* bih  = (const float*)d_in[5];
    const float* bhh  = (const float*)d_in[6];
    const float* fcw  = (const float*)d_in[7];
    const float* fcb  = (const float*)d_in[8];
    const int*   adj  = (const int*)d_in[9];

    float* out = (float*)d_out;
    float* out_pred = out;
    float* out_res  = out + (size_t)NN_ * FD;
    float* out_adj  = out + (size_t)NN_ * FD * 4;

    // ws layout (~92 MB):
    char* ws = (char*)d_ws;
    float*          dinv  = (float*)ws;                          //        0 (49,152)
    unsigned short* dinvb = (unsigned short*)(ws + 49152);       // bf16 dinv (24,576)
    unsigned short* R1    = (unsigned short*)(ws + 73728);       // uT -> h  (6,291,456)
    unsigned short* H1    = (unsigned short*)(ws + 6365184);     // h pong   (6,291,456)
    unsigned short* XT    = (unsigned short*)(ws + 12656640);    // xt       (6,291,456)
    unsigned short* wb    = (unsigned short*)(ws + 18948096);    // weights  (3,538,944)
    unsigned char*  abits = (unsigned char*)(ws + 22487040);     // bits     (6,291,456)
    unsigned short* pbuf  = (unsigned short*)(ws + 28778496);    // partials (25,165,824)
    unsigned short* gX2   = (unsigned short*)(ws + 53944320);    // Wx gates (25,165,824)
    float*          cbuf  = (float*)(ws + 79110144);             // c f32    (12,582,912)
    const unsigned short* wihb = wb;
    const unsigned short* whhb = wb + 786432;
    const unsigned short* fcwb = wb + 1572864;
    (void)ws_size; (void)in_sizes; (void)n_in; (void)out_size;

    // adj pass + weight cvt + fused UNSCALED gemm_xw (blocks 4096..4863)
    adjxw<<<dim3(4864), 256, 0, stream>>>(adj, out_adj, abits, dinv, dinvb,
                                          wih, whh, fcw, wb, gnnw, x, R1 /*uT*/);
    gemm_agg<<<dim3(768), 256, 0, stream>>>(abits, R1 /*uT*/, dinvb, dinv, pbuf);
    agg_reduce<<<dim3(1536), 256, 0, stream>>>(pbuf, dinv, gnnb, XT);
    // t=0: xt@wih + biases -> gX2; cell0 -> cbuf, h -> R1 (uT dead now)
    lstm_gate<<<dim3(768), 256, 0, stream>>>(XT, wihb, bih, bhh, gX2, cbuf, R1);
    // steps 1..4, ping-pong R1 <-> H1 (h_last lands in R1)
    lstm_step<<<dim3(768), 256, 0, stream>>>(R1, whhb, gX2, cbuf, H1);
    lstm_step<<<dim3(768), 256, 0, stream>>>(H1, whhb, gX2, cbuf, R1);
    lstm_step<<<dim3(768), 256, 0, stream>>>(R1, whhb, gX2, cbuf, H1);
    lstm_step<<<dim3(768), 256, 0, stream>>>(H1, whhb, gX2, cbuf, R1);
    fc_final<<<dim3(4, 64), 256, 0, stream>>>(R1, fcwb, fcb, x, out_pred, out_res);
}

// Round 10
// 572.911 us; speedup vs baseline: 1.0265x; 1.0265x over previous
//
#include <hip/hip_runtime.h>
#include <stdint.h>

// MGMCGCN — 3x (binary-GCN + 5-step LSTM + fc/tanh).
// Dtypes: float inputs f32, adj int32, ALL OUTPUTS f32. Internal bf16 MFMA.
// N=4096, F=H=256, K=3, T=5, G=4H=1024.
// R10 change log:
//  - REVERT R9 nontemporal hints (defeated L2 write-combining, +15us).
//  - adj_out writes staged through LDS -> per-instruction contiguous 1KB
//    global stores (was 16B/lane at 48B stride = partial-line writes; adjxw
//    measured 40% BW with writes = 2/3 of traffic).
//  - everything else = R6-verified bodies (572.6 us best).
#define NN_ 4096
#define FD 256
#define HD 256
#define KC 3
#define GD 1024
#define SA 40      // padded LDS pitch (shorts) for fused-xw staging
#define BPITCH 144 // bitsA LDS row pitch (bytes)

typedef __attribute__((ext_vector_type(4))) unsigned int vu4;     // 16 B
typedef __attribute__((ext_vector_type(4))) int vi4;              // 16 B
typedef __attribute__((ext_vector_type(4))) float vf4;            // 16 B
typedef __attribute__((ext_vector_type(4))) unsigned short vus4;  // 8 B
typedef __attribute__((ext_vector_type(8))) short short8;         // bf16x8 MFMA frag
typedef __attribute__((ext_vector_type(4))) float f32x4;          // MFMA acc

typedef __attribute__((address_space(1))) const void GV;
typedef __attribute__((address_space(3))) void LV;
__device__ __forceinline__ void gl16(const void* g, void* l) {
    __builtin_amdgcn_global_load_lds((GV*)g, (LV*)l, 16, 0, 0);
}

__device__ __forceinline__ float b2f(unsigned short u) {
    unsigned int v = ((unsigned int)u) << 16; float f; __builtin_memcpy(&f, &v, 4); return f;
}
__device__ __forceinline__ unsigned short f2b(float x) {
    unsigned int u; __builtin_memcpy(&u, &x, 4);
    u = (u + 0x7FFFu + ((u >> 16) & 1u)) >> 16;   // RNE
    return (unsigned short)u;
}
__device__ __forceinline__ void cvt8(const float* __restrict__ g, unsigned short* o) {
    vf4 a = *(const vf4*)g, b = *(const vf4*)(g + 4);
    o[0] = f2b(a[0]); o[1] = f2b(a[1]); o[2] = f2b(a[2]); o[3] = f2b(a[3]);
    o[4] = f2b(b[0]); o[5] = f2b(b[1]); o[6] = f2b(b[2]); o[7] = f2b(b[3]);
}
// fast transcendentals: v_rcp_f32-based; correct saturation at +/-inf.
__device__ __forceinline__ float frcp(float x) { return __builtin_amdgcn_rcpf(x); }
__device__ __forceinline__ float sigm(float v) { return frcp(1.f + __expf(-v)); }
__device__ __forceinline__ float ftanh(float v) { return 1.f - 2.f * frcp(__expf(2.f * v) + 1.f); }

// ---------------------------------------------------------------------------
// adjxw: blocks 0..4095 = adj pass (adj->f32 copy via LDS-staged COALESCED
// stores, bit planes, dinv f32+bf16; blocks <864 also convert
// [wih|whh|fcw]->wb). Blocks 4096..4863 = gemm_xw (UNSCALED u = x@gnn_w,
// transposed store uT[k][h][j]). 15 KB LDS union.
// ---------------------------------------------------------------------------
__global__ __launch_bounds__(256) void adjxw(const int* __restrict__ adj,
        float* __restrict__ adj_out, unsigned char* __restrict__ abits,
        float* __restrict__ dinv, unsigned short* __restrict__ dinvb,
        const float* __restrict__ wih, const float* __restrict__ whh,
        const float* __restrict__ fcw, unsigned short* __restrict__ wb,
        const float* __restrict__ gnnw, const float* __restrict__ x,
        unsigned short* __restrict__ uT) {
    const int bid = blockIdx.x, t = threadIdx.x;
    __shared__ __align__(16) char smem[15360];   // union: xw 10KB | adj 15KB
    if (bid >= 4096) {
        // ---------------- fused gemm_xw (unscaled) ----------------
        unsigned short* sA = (unsigned short*)smem;            // 64*SA shorts
        unsigned short* sB = sA + 64 * SA;
        const int b2 = bid - 4096;
        const int k = b2 >> 8, rem = b2 & 255, bn = rem >> 2, bg = rem & 3;
        const int lane = t & 63, wave = t >> 6;
        const int m = lane & 15, q = lane >> 4, ko = q * 8;
        const int h0 = bg * 64;
        f32x4 acc[4] = {};
        const float* A0 = x + (size_t)(bn * 64) * FD;
        const float* B0 = gnnw + (size_t)k * FD * HD;
        const int r = t >> 2, c8 = (t & 3) << 3;
        const int fB = t >> 3, c8B = (t & 7) << 3;
        for (int k0 = 0; k0 < FD; k0 += 32) {
            alignas(16) unsigned short tA[8], tB[8];
            cvt8(A0 + (size_t)r * FD + k0 + c8, tA);
            *(vu4*)(sA + r * SA + c8) = *(vu4*)tA;
            cvt8(B0 + (size_t)(k0 + fB) * HD + h0 + c8B, tB);
#pragma unroll
            for (int e = 0; e < 8; ++e) sB[(c8B + e) * SA + fB] = tB[e];
            __syncthreads();
            short8 af = *(const short8*)(sA + (wave * 16 + m) * SA + ko);
#pragma unroll
            for (int ct = 0; ct < 4; ++ct) {
                short8 bf = *(const short8*)(sB + (ct * 16 + m) * SA + ko);
                acc[ct] = __builtin_amdgcn_mfma_f32_16x16x32_bf16(af, bf, acc[ct], 0, 0, 0);
            }
            __syncthreads();
        }
        unsigned short* uTk = uT + (size_t)k * HD * NN_;
#pragma unroll
        for (int ct = 0; ct < 4; ++ct)
#pragma unroll
            for (int r2 = 0; r2 < 4; ++r2) {
                int col = h0 + ct * 16 + m;
                int row = bn * 64 + wave * 16 + q * 4 + r2;
                uTk[(size_t)col * NN_ + row] = f2b(acc[ct][r2]);
            }
        return;
    }
    // ---------------- adj pass ----------------
    unsigned char* nib0 = (unsigned char*)smem;        // [3][1024] = 3072 B
    float* stagef = (float*)(smem + 3072);             // 3072 floats = 12288 B
    float* r0 = (float*)(smem + 3072);                 // alias stage (post-loop)
    float* r1 = r0 + 256;
    float* r2 = r1 + 256;
    const int i = bid;
    if (i < 864) {   // one-time weight conversion: wih|whh|fcw (exactly 864*2048)
        size_t e = ((size_t)i * 256 + t) * 8;
        const float* src; size_t off;
        if (e < 786432)       { src = wih; off = e; }
        else if (e < 1572864) { src = whh; off = e - 786432; }
        else                  { src = fcw; off = e - 1572864; }
        alignas(16) unsigned short o[8];
        cvt8(src + off, o);
        *(vu4*)(wb + e) = *(vu4*)o;
    }
    const int* src = adj + (size_t)i * 12288;
    float* dstf = adj_out + (size_t)i * 12288;
    float s0 = 0.f, s1 = 0.f, s2 = 0.f;
    for (int it = 0; it < 4; ++it) {
        int p = it * 256 + t;
        int jq = p * 4;
        vi4 a = *(const vi4*)(src + jq * 3);
        vi4 b = *(const vi4*)(src + jq * 3 + 4);
        vi4 c = *(const vi4*)(src + jq * 3 + 8);
        int vv[12] = {a[0],a[1],a[2],a[3],b[0],b[1],b[2],b[3],c[0],c[1],c[2],c[3]};
        float ff[12];
#pragma unroll
        for (int e = 0; e < 12; ++e) ff[e] = vv[e] ? 1.f : 0.f;
        vf4 w0 = {ff[0],ff[1],ff[2],ff[3]}, w1 = {ff[4],ff[5],ff[6],ff[7]}, w2 = {ff[8],ff[9],ff[10],ff[11]};
        // stage to LDS (thread-major dense), then coalesced global write
        *(vf4*)(stagef + t * 12)     = w0;
        *(vf4*)(stagef + t * 12 + 4) = w1;
        *(vf4*)(stagef + t * 12 + 8) = w2;
#pragma unroll
        for (int k = 0; k < 3; ++k) {
            unsigned int nb = (vv[k] ? 1u : 0u) | (vv[3 + k] ? 2u : 0u)
                            | (vv[6 + k] ? 4u : 0u) | (vv[9 + k] ? 8u : 0u);
            nib0[k * 1024 + p] = (unsigned char)nb;
        }
        s0 += ff[0] + ff[3] + ff[6] + ff[9];
        s1 += ff[1] + ff[4] + ff[7] + ff[10];
        s2 += ff[2] + ff[5] + ff[8] + ff[11];
        __syncthreads();
        float* dsweep = dstf + it * 3072;
#pragma unroll
        for (int wv = 0; wv < 3; ++wv)
            *(vf4*)(dsweep + wv * 1024 + t * 4) = *(const vf4*)(stagef + wv * 1024 + t * 4);
        __syncthreads();
    }
    r0[t] = s0; r1[t] = s1; r2[t] = s2;
    __syncthreads();
#pragma unroll
    for (int k = 0; k < 3; ++k) {
        unsigned int b0 = (unsigned int)nib0[k * 1024 + t * 4 + 0] | ((unsigned int)nib0[k * 1024 + t * 4 + 1] << 4);
        unsigned int b1 = (unsigned int)nib0[k * 1024 + t * 4 + 2] | ((unsigned int)nib0[k * 1024 + t * 4 + 3] << 4);
        *(unsigned short*)(abits + ((size_t)k * NN_ + i) * 512 + t * 2) =
            (unsigned short)(b0 | (b1 << 8));
    }
    for (int off = 128; off > 0; off >>= 1) {
        if (t < off) { r0[t] += r0[t + off]; r1[t] += r1[t + off]; r2[t] += r2[t + off]; }
        __syncthreads();
    }
    if (t == 0) {
        float d0 = 1.f / sqrtf(1.f + r0[0]);
        float d1 = 1.f / sqrtf(1.f + r1[0]);
        float d2 = 1.f / sqrtf(1.f + r2[0]);
        dinv[i]           = d0; dinvb[i]            = f2b(d0);
        dinv[NN_ + i]     = d1; dinvb[NN_ + i]      = f2b(d1);
        dinv[2 * NN_ + i] = d2; dinvb[2 * NN_ + i]  = f2b(d2);
    }
}

// ---------------------------------------------------------------------------
// gemm_agg v7: 128x128 tiles, 2x2 waves, j-split s=4 (grid 768, XCD swizzle).
// K-step 64 via two 32-j half-buffers (sB0/sB1, 64B pitch each) -> one
// barrier pair per 32 MFMA. A expanded from bit-plane to bf16(dinv_j).
// ---------------------------------------------------------------------------
__global__ __launch_bounds__(256) void gemm_agg(const unsigned char* __restrict__ abits,
        const unsigned short* __restrict__ uT, const unsigned short* __restrict__ dinvb,
        const float* __restrict__ dinv, unsigned short* __restrict__ pbuf) {
    __shared__ __align__(16) unsigned char bitsA[128 * BPITCH];    // 18 KB
    __shared__ __align__(16) unsigned short sB0[128 * 32];          // 8 KB (j half 0)
    __shared__ __align__(16) unsigned short sB1[128 * 32];          // 8 KB (j half 1)
    __shared__ __align__(16) unsigned short sDv[1024];              // 2 KB dinv slice
    const int d = blockIdx.x;                  // 0..767
    const int w = (d & 7) * 96 + (d >> 3);     // bijective XCD-chunked remap
    const int bh = w & 1, bi = (w >> 1) & 31, z = w >> 6;
    const int k = z >> 2, s = z & 3;
    const int t = threadIdx.x, lane = t & 63, wave = t >> 6;
    const int wi = wave & 1, wh = wave >> 1;
    const int m = lane & 15, q = lane >> 4, ko = q * 8;
    const int i0 = bi * 128, h0 = bh * 128, jbase = s * 1024;
    {   // stage the A bit-tile once: 128 rows x 128 B
        const int row = t >> 1, half = t & 1;
        const unsigned char* bsrc = abits + ((size_t)k * NN_ + i0 + row) * 512 + s * 128 + half * 64;
        unsigned char* bdst = bitsA + row * BPITCH + half * 64;
        vu4 v0 = *(const vu4*)(bsrc);
        vu4 v1 = *(const vu4*)(bsrc + 16);
        vu4 v2 = *(const vu4*)(bsrc + 32);
        vu4 v3 = *(const vu4*)(bsrc + 48);
        *(vu4*)(bdst)      = v0;
        *(vu4*)(bdst + 16) = v1;
        *(vu4*)(bdst + 32) = v2;
        *(vu4*)(bdst + 48) = v3;
    }
    if (t < 128)   // stage the dinv_j slice for this j-chunk (1024 bf16)
        *(vu4*)(sDv + t * 8) = *(const vu4*)(dinvb + (size_t)k * NN_ + jbase + t * 8);
    f32x4 acc[4][4] = {};
    const int lrow = lane >> 2, lcol = (lane & 3) << 3;
    const unsigned short* Bg0 = uT + ((size_t)(k * 256 + h0 + wave * 32 + lrow)) * NN_ + jbase + lcol;
    const unsigned short* Bg1 = Bg0 + (size_t)16 * NN_;
    unsigned short* lB00 = sB0 + (wave * 32) * 32;
    unsigned short* lB01 = lB00 + 16 * 32;
    unsigned short* lB10 = sB1 + (wave * 32) * 32;
    unsigned short* lB11 = lB10 + 16 * 32;
    const int arowb = (wi * 64 + m) * BPITCH + q;
    for (int j0 = 0; j0 < 1024; j0 += 64) {
        gl16(Bg0 + j0, lB00);
        gl16(Bg1 + j0, lB01);
        gl16(Bg0 + j0 + 32, lB10);
        gl16(Bg1 + j0 + 32, lB11);
        __syncthreads();
        const int jby = j0 >> 3;
        short8 dv0 = *(const short8*)(sDv + j0 + ko);
        short8 dv1 = *(const short8*)(sDv + j0 + 32 + ko);
        short8 af0[4], af1[4];
#pragma unroll
        for (int rt = 0; rt < 4; ++rt) {
            unsigned int by0 = bitsA[arowb + rt * 16 * BPITCH + jby];
            unsigned int by1 = bitsA[arowb + rt * 16 * BPITCH + jby + 4];
#pragma unroll
            for (int e = 0; e < 8; ++e) {
                af0[rt][e] = (short)(((by0 >> e) & 1u) ? dv0[e] : (short)0);
                af1[rt][e] = (short)(((by1 >> e) & 1u) ? dv1[e] : (short)0);
            }
        }
#pragma unroll
        for (int ct = 0; ct < 4; ++ct) {
            short8 bf0 = *(const short8*)(sB0 + (wh * 64 + ct * 16 + m) * 32 + ko);
#pragma unroll
            for (int rt = 0; rt < 4; ++rt)
                acc[rt][ct] = __builtin_amdgcn_mfma_f32_16x16x32_bf16(af0[rt], bf0, acc[rt][ct], 0, 0, 0);
        }
#pragma unroll
        for (int ct = 0; ct < 4; ++ct) {
            short8 bf1 = *(const short8*)(sB1 + (wh * 64 + ct * 16 + m) * 32 + ko);
#pragma unroll
            for (int rt = 0; rt < 4; ++rt)
                acc[rt][ct] = __builtin_amdgcn_mfma_f32_16x16x32_bf16(af1[rt], bf1, acc[rt][ct], 0, 0, 0);
        }
        __syncthreads();
    }
    const int addself = ((bi >> 3) == s);
#pragma unroll
    for (int rt = 0; rt < 4; ++rt)
#pragma unroll
        for (int ct = 0; ct < 4; ++ct)
#pragma unroll
            for (int r2 = 0; r2 < 4; ++r2) {
                int row = i0 + wi * 64 + rt * 16 + q * 4 + r2;
                int col = h0 + wh * 64 + ct * 16 + m;
                float v = acc[rt][ct][r2];
                if (addself)
                    v += dinv[(size_t)k * NN_ + row]
                       * b2f(uT[((size_t)k * 256 + col) * NN_ + row]);
                pbuf[(((size_t)s * 3 + k) * NN_ + row) * 256 + col] = f2b(v);
            }
}

// ---------------------------------------------------------------------------
// agg_reduce: xt[k][i][h] = f2b(dinv[k][i] * (sum_s pbuf[s]) + gnnb[k][h])
// ---------------------------------------------------------------------------
__global__ __launch_bounds__(256) void agg_reduce(const unsigned short* __restrict__ pbuf,
        const float* __restrict__ dinv, const float* __restrict__ gnnb,
        unsigned short* __restrict__ xt) {
    size_t e8 = ((size_t)blockIdx.x * 256 + threadIdx.x) * 8;
    int k = (int)(e8 >> 20);
    int i = (int)((e8 >> 8) & 4095);
    int h = (int)(e8 & 255);
    float di = dinv[k * NN_ + i];
    const size_t KIH = (size_t)KC * NN_ * HD;
    alignas(16) unsigned short p0[8], p1[8], p2[8], p3[8], o[8];
    *(vu4*)p0 = *(const vu4*)(pbuf + 0 * KIH + e8);
    *(vu4*)p1 = *(const vu4*)(pbuf + 1 * KIH + e8);
    *(vu4*)p2 = *(const vu4*)(pbuf + 2 * KIH + e8);
    *(vu4*)p3 = *(const vu4*)(pbuf + 3 * KIH + e8);
#pragma unroll
    for (int e = 0; e < 8; ++e) {
        float v = b2f(p0[e]) + b2f(p1[e]) + b2f(p2[e]) + b2f(p3[e]);
        o[e] = f2b(di * v + gnnb[k * HD + h + e]);
    }
    *(vu4*)(xt + e8) = *(vu4*)o;
}

// ---------------------------------------------------------------------------
// lstm_gate (t=0): NT GEMM xt @ wih^T via gl16 (K-step 64, half-buffers);
// +bih+bhh -> gX2; fused t=0 cell. Grid 768, XCD swizzle.
// ---------------------------------------------------------------------------
__global__ __launch_bounds__(256) void lstm_gate(const unsigned short* __restrict__ A,
        const unsigned short* __restrict__ W, const float* __restrict__ b1,
        const float* __restrict__ b2, unsigned short* __restrict__ gX2,
        float* __restrict__ cbuf, unsigned short* __restrict__ hbuf) {
    __shared__ __align__(16) unsigned short sA0[128 * 32], sA1[128 * 32];   // 16 KB
    __shared__ __align__(16) unsigned short sB0[128 * 32], sB1[128 * 32];   // 16 KB
    const int d = blockIdx.x;
    const int w = (d & 7) * 96 + (d >> 3);
    const int chb = w & 7, bn = w >> 3;
    const int t = threadIdx.x, lane = t & 63, wave = t >> 6;
    const int m = lane & 15, q = lane >> 4, ko = q * 8;
    const int kk = bn >> 5;
    f32x4 acc[2][2][4] = {};
    const int lrow = lane >> 2, lcol = (lane & 3) << 3;
    const unsigned short* A0 = A + (size_t)bn * 128 * 256;
    const unsigned short* W0 = W + (size_t)kk * GD * 256 + (size_t)chb * 32 * 256;
    const unsigned short* Ag0 = A0 + (size_t)(wave * 32 + lrow) * 256 + lcol;
    const unsigned short* Ag1 = Ag0 + 16 * 256;
    const unsigned short* Bg0 = W0 + (size_t)(wave * 256 + lrow) * 256 + lcol;
    const unsigned short* Bg1 = Bg0 + 16 * 256;
    unsigned short* lA00 = sA0 + (wave * 32) * 32; unsigned short* lA01 = lA00 + 16 * 32;
    unsigned short* lA10 = sA1 + (wave * 32) * 32; unsigned short* lA11 = lA10 + 16 * 32;
    unsigned short* lB00 = sB0 + (wave * 32) * 32; unsigned short* lB01 = lB00 + 16 * 32;
    unsigned short* lB10 = sB1 + (wave * 32) * 32; unsigned short* lB11 = lB10 + 16 * 32;
    for (int k0 = 0; k0 < 256; k0 += 64) {
        gl16(Ag0 + k0, lA00);      gl16(Ag1 + k0, lA01);
        gl16(Ag0 + k0 + 32, lA10); gl16(Ag1 + k0 + 32, lA11);
        gl16(Bg0 + k0, lB00);      gl16(Bg1 + k0, lB01);
        gl16(Bg0 + k0 + 32, lB10); gl16(Bg1 + k0 + 32, lB11);
        __syncthreads();
        short8 af0[2], af1[2];
#pragma unroll
        for (int rt = 0; rt < 2; ++rt) {
            af0[rt] = *(const short8*)(sA0 + (wave * 32 + rt * 16 + m) * 32 + ko);
            af1[rt] = *(const short8*)(sA1 + (wave * 32 + rt * 16 + m) * 32 + ko);
        }
#pragma unroll
        for (int g = 0; g < 4; ++g)
#pragma unroll
            for (int cc = 0; cc < 2; ++cc) {
                short8 bf0 = *(const short8*)(sB0 + (g * 32 + cc * 16 + m) * 32 + ko);
#pragma unroll
                for (int rt = 0; rt < 2; ++rt)
                    acc[rt][cc][g] = __builtin_amdgcn_mfma_f32_16x16x32_bf16(af0[rt], bf0, acc[rt][cc][g], 0, 0, 0);
                short8 bf1 = *(const short8*)(sB1 + (g * 32 + cc * 16 + m) * 32 + ko);
#pragma unroll
                for (int rt = 0; rt < 2; ++rt)
                    acc[rt][cc][g] = __builtin_amdgcn_mfma_f32_16x16x32_bf16(af1[rt], bf1, acc[rt][cc][g], 0, 0, 0);
            }
        __syncthreads();
    }
#pragma unroll
    for (int rt = 0; rt < 2; ++rt)
#pragma unroll
        for (int cc = 0; cc < 2; ++cc)
#pragma unroll
            for (int r2 = 0; r2 < 4; ++r2) {
                int row = bn * 128 + wave * 32 + rt * 16 + q * 4 + r2;
                int ch = chb * 32 + cc * 16 + m;
                size_t goff = ((size_t)row * 256 + ch) * 4;
                size_t coff = (size_t)row * 256 + ch;
                float v[4];
                vus4 o;
#pragma unroll
                for (int g = 0; g < 4; ++g) {
                    v[g] = acc[rt][cc][g][r2]
                         + b1[kk * GD + g * 256 + ch] + b2[kk * GD + g * 256 + ch];
                    o[g] = f2b(v[g]);
                }
                *(vus4*)(gX2 + goff) = o;
                float cn = sigm(v[0]) * ftanh(v[2]);
                cbuf[coff] = cn;
                hbuf[coff] = f2b(sigm(v[3]) * ftanh(cn));
            }
}

// ---------------------------------------------------------------------------
// lstm_step: NT GEMM h_prev @ whh^T (K-step 64, half-buffers); g = v + gX2;
// cell update with cbuf (f32); write c, h_next (ping-pong, no race).
// ---------------------------------------------------------------------------
__global__ __launch_bounds__(256) void lstm_step(const unsigned short* __restrict__ A,
        const unsigned short* __restrict__ W, const unsigned short* __restrict__ gX2,
        float* __restrict__ cbuf, unsigned short* __restrict__ hbuf) {
    __shared__ __align__(16) unsigned short sA0[128 * 32], sA1[128 * 32];   // 16 KB
    __shared__ __align__(16) unsigned short sB0[128 * 32], sB1[128 * 32];   // 16 KB
    const int d = blockIdx.x;
    const int w = (d & 7) * 96 + (d >> 3);
    const int chb = w & 7, bn = w >> 3;
    const int t = threadIdx.x, lane = t & 63, wave = t >> 6;
    const int m = lane & 15, q = lane >> 4, ko = q * 8;
    const int kk = bn >> 5;
    f32x4 acc[2][2][4] = {};
    const int lrow = lane >> 2, lcol = (lane & 3) << 3;
    const unsigned short* A0 = A + (size_t)bn * 128 * 256;
    const unsigned short* W0 = W + (size_t)kk * GD * 256 + (size_t)chb * 32 * 256;
    const unsigned short* Ag0 = A0 + (size_t)(wave * 32 + lrow) * 256 + lcol;
    const unsigned short* Ag1 = Ag0 + 16 * 256;
    const unsigned short* Bg0 = W0 + (size_t)(wave * 256 + lrow) * 256 + lcol;
    const unsigned short* Bg1 = Bg0 + 16 * 256;
    unsigned short* lA00 = sA0 + (wave * 32) * 32; unsigned short* lA01 = lA00 + 16 * 32;
    unsigned short* lA10 = sA1 + (wave * 32) * 32; unsigned short* lA11 = lA10 + 16 * 32;
    unsigned short* lB00 = sB0 + (wave * 32) * 32; unsigned short* lB01 = lB00 + 16 * 32;
    unsigned short* lB10 = sB1 + (wave * 32) * 32; unsigned short* lB11 = lB10 + 16 * 32;
    for (int k0 = 0; k0 < 256; k0 += 64) {
        gl16(Ag0 + k0, lA00);      gl16(Ag1 + k0, lA01);
        gl16(Ag0 + k0 + 32, lA10); gl16(Ag1 + k0 + 32, lA11);
        gl16(Bg0 + k0, lB00);      gl16(Bg1 + k0, lB01);
        gl16(Bg0 + k0 + 32, lB10); gl16(Bg1 + k0 + 32, lB11);
        __syncthreads();
        short8 af0[2], af1[2];
#pragma unroll
        for (int rt = 0; rt < 2; ++rt) {
            af0[rt] = *(const short8*)(sA0 + (wave * 32 + rt * 16 + m) * 32 + ko);
            af1[rt] = *(const short8*)(sA1 + (wave * 32 + rt * 16 + m) * 32 + ko);
        }
#pragma unroll
        for (int g = 0; g < 4; ++g)
#pragma unroll
            for (int cc = 0; cc < 2; ++cc) {
                short8 bf0 = *(const short8*)(sB0 + (g * 32 + cc * 16 + m) * 32 + ko);
#pragma unroll
                for (int rt = 0; rt < 2; ++rt)
                    acc[rt][cc][g] = __builtin_amdgcn_mfma_f32_16x16x32_bf16(af0[rt], bf0, acc[rt][cc][g], 0, 0, 0);
                short8 bf1 = *(const short8*)(sB1 + (g * 32 + cc * 16 + m) * 32 + ko);
#pragma unroll
                for (int rt = 0; rt < 2; ++rt)
                    acc[rt][cc][g] = __builtin_amdgcn_mfma_f32_16x16x32_bf16(af1[rt], bf1, acc[rt][cc][g], 0, 0, 0);
            }
        __syncthreads();
    }
#pragma unroll
    for (int rt = 0; rt < 2; ++rt)
#pragma unroll
        for (int cc = 0; cc < 2; ++cc)
#pragma unroll
            for (int r2 = 0; r2 < 4; ++r2) {
                int row = bn * 128 + wave * 32 + rt * 16 + q * 4 + r2;
                int ch = chb * 32 + cc * 16 + m;
                size_t goff = ((size_t)row * 256 + ch) * 4;
                size_t coff = (size_t)row * 256 + ch;
                vus4 gv = *(const vus4*)(gX2 + goff);
                float iv = acc[rt][cc][0][r2] + b2f(gv[0]);
                float fv = acc[rt][cc][1][r2] + b2f(gv[1]);
                float gg = acc[rt][cc][2][r2] + b2f(gv[2]);
                float ov = acc[rt][cc][3][r2] + b2f(gv[3]);
                float cn = sigm(fv) * cbuf[coff] + sigm(iv) * ftanh(gg);
                cbuf[coff] = cn;
                hbuf[coff] = f2b(sigm(ov) * ftanh(cn));
            }
}

// ---------------------------------------------------------------------------
// fc_final: one block computes 64x64 output for ALL 3 k (acc[3][4]), then the
// final epilogue inline: delta_k = tanh(h@fcw^T + fcb); pred/res from x+delta.
// ---------------------------------------------------------------------------
__global__ __launch_bounds__(256) void fc_final(const unsigned short* __restrict__ A,
        const unsigned short* __restrict__ W, const float* __restrict__ fcb,
        const float* __restrict__ x, float* __restrict__ pred, float* __restrict__ res) {
    __shared__ __align__(16) unsigned short sA[3][64 * 32], sB[3][64 * 32];  // 24 KB
    const int bg = blockIdx.x, bn = blockIdx.y;
    const int t = threadIdx.x, lane = t & 63, wave = t >> 6;
    const int m = lane & 15, q = lane >> 4, ko = q * 8;
    f32x4 acc[3][4] = {};
    const int lrow = lane >> 2, lcol = (lane & 3) << 3;
    const unsigned short* Ag[3]; const unsigned short* Bg[3];
#pragma unroll
    for (int k = 0; k < 3; ++k) {
        Ag[k] = A + ((size_t)k * NN_ + bn * 64 + wave * 16 + lrow) * HD + lcol;
        Bg[k] = W + ((size_t)k * FD + bg * 64 + wave * 16 + lrow) * HD + lcol;
    }
    for (int k0 = 0; k0 < HD; k0 += 32) {
#pragma unroll
        for (int k = 0; k < 3; ++k) {
            gl16(Ag[k] + k0, sA[k] + (wave * 16) * 32);
            gl16(Bg[k] + k0, sB[k] + (wave * 16) * 32);
        }
        __syncthreads();
#pragma unroll
        for (int k = 0; k < 3; ++k) {
            short8 af = *(const short8*)(sA[k] + (wave * 16 + m) * 32 + ko);
#pragma unroll
            for (int ct = 0; ct < 4; ++ct) {
                short8 bf = *(const short8*)(sB[k] + (ct * 16 + m) * 32 + ko);
                acc[k][ct] = __builtin_amdgcn_mfma_f32_16x16x32_bf16(af, bf, acc[k][ct], 0, 0, 0);
            }
        }
        __syncthreads();
    }
#pragma unroll
    for (int ct = 0; ct < 4; ++ct)
#pragma unroll
        for (int r2 = 0; r2 < 4; ++r2) {
            int col = bg * 64 + ct * 16 + m;
            int row = bn * 64 + wave * 16 + q * 4 + r2;
            float d0 = ftanh(acc[0][ct][r2] + fcb[col]);
            float d1 = ftanh(acc[1][ct][r2] + fcb[FD + col]);
            float d2 = ftanh(acc[2][ct][r2] + fcb[2 * FD + col]);
            float xf = x[(size_t)row * FD + col];
            bool sg = (col >= 10) && (col < 253);
            float dm = (d0 + d1 + d2) * (1.f / 3.f);
            float p = xf + dm; if (sg) p = sigm(p);
            pred[(size_t)row * FD + col] = p;
            float z0 = xf + d0; if (sg) z0 = sigm(z0);
            float z1 = xf + d1; if (sg) z1 = sigm(z1);
            float z2 = xf + d2; if (sg) z2 = sigm(z2);
            size_t rb = ((size_t)row * FD + col) * 3;
            res[rb] = z0; res[rb + 1] = z1; res[rb + 2] = z2;
        }
}

extern "C" void kernel_launch(void* const* d_in, const int* in_sizes, int n_in,
                              void* d_out, int out_size, void* d_ws, size_t ws_size,
                              hipStream_t stream) {
    const float* x    = (const float*)d_in[0];
    const float* gnnw = (const float*)d_in[1];
    const float* gnnb = (const float*)d_in[2];
    const float* wih  = (const float*)d_in[3];
    const float* whh  = (const float*)d_in[4];
    const float* bih  = (const float*)d_in[5];
    const float* bhh  = (const float*)d_in[6];
    const float* fcw  = (const float*)d_in[7];
    const float* fcb  = (const float*)d_in[8];
    const int*   adj  = (const int*)d_in[9];

    float* out = (float*)d_out;
    float* out_pred = out;
    float* out_res  = out + (size_t)NN_ * FD;
    float* out_adj  = out + (size_t)NN_ * FD * 4;

    // ws layout (~92 MB):
    char* ws = (char*)d_ws;
    float*          dinv  = (float*)ws;                          //        0 (49,152)
    unsigned short* dinvb = (unsigned short*)(ws + 49152);       // bf16 dinv (24,576)
    unsigned short* R1    = (unsigned short*)(ws + 73728);       // uT -> h  (6,291,456)
    unsigned short* H1    = (unsigned short*)(ws + 6365184);     // h pong   (6,291,456)
    unsigned short* XT    = (unsigned short*)(ws + 12656640);    // xt       (6,291,456)
    unsigned short* wb    = (unsigned short*)(ws + 18948096);    // weights  (3,538,944)
    unsigned char*  abits = (unsigned char*)(ws + 22487040);     // bits     (6,291,456)
    unsigned short* pbuf  = (unsigned short*)(ws + 28778496);    // partials (25,165,824)
    unsigned short* gX2   = (unsigned short*)(ws + 53944320);    // Wx gates (25,165,824)
    float*          cbuf  = (float*)(ws + 79110144);             // c f32    (12,582,912)
    const unsigned short* wihb = wb;
    const unsigned short* whhb = wb + 786432;
    const unsigned short* fcwb = wb + 1572864;
    (void)ws_size; (void)in_sizes; (void)n_in; (void)out_size;

    // adj pass + weight cvt + fused UNSCALED gemm_xw (blocks 4096..4863)
    adjxw<<<dim3(4864), 256, 0, stream>>>(adj, out_adj, abits, dinv, dinvb,
                                          wih, whh, fcw, wb, gnnw, x, R1 /*uT*/);
    gemm_agg<<<dim3(768), 256, 0, stream>>>(abits, R1 /*uT*/, dinvb, dinv, pbuf);
    agg_reduce<<<dim3(1536), 256, 0, stream>>>(pbuf, dinv, gnnb, XT);
    // t=0: xt@wih + biases -> gX2; cell0 -> cbuf, h -> R1 (uT dead now)
    lstm_gate<<<dim3(768), 256, 0, stream>>>(XT, wihb, bih, bhh, gX2, cbuf, R1);
    // steps 1..4, ping-pong R1 <-> H1 (h_last lands in R1)
    lstm_step<<<dim3(768), 256, 0, stream>>>(R1, whhb, gX2, cbuf, H1);
    lstm_step<<<dim3(768), 256, 0, stream>>>(H1, whhb, gX2, cbuf, R1);
    lstm_step<<<dim3(768), 256, 0, stream>>>(R1, whhb, gX2, cbuf, H1);
    lstm_step<<<dim3(768), 256, 0, stream>>>(H1, whhb, gX2, cbuf, R1);
    fc_final<<<dim3(4, 64), 256, 0, stream>>>(R1, fcwb, fcb, x, out_pred, out_res);
}

// Round 11
// 571.272 us; speedup vs baseline: 1.0295x; 1.0029x over previous
//
#include <hip/hip_runtime.h>
#include <stdint.h>

// MGMCGCN — 3x (binary-GCN + 5-step LSTM + fc/tanh).
// Dtypes: float inputs f32, adj int32, ALL OUTPUTS f32. Internal bf16 MFMA.
// N=4096, F=H=256, K=3, T=5, G=4H=1024.
// R11 change log:
//  - adjxw: all 12 adj loads issued UP-FRONT (MLP 12/thread vs 3; adjxw is
//    latency-bound at 40% BW — R9 nt and R10 write-coalescing both ruled out).
//    Direct strided stores restored (R10 LDS staging was neutral).
//  - everything else = R6-verified bodies (572.6/572.9 us).
#define NN_ 4096
#define FD 256
#define HD 256
#define KC 3
#define GD 1024
#define SA 40      // padded LDS pitch (shorts) for fused-xw staging
#define BPITCH 144 // bitsA LDS row pitch (bytes)

typedef __attribute__((ext_vector_type(4))) unsigned int vu4;     // 16 B
typedef __attribute__((ext_vector_type(4))) int vi4;              // 16 B
typedef __attribute__((ext_vector_type(4))) float vf4;            // 16 B
typedef __attribute__((ext_vector_type(4))) unsigned short vus4;  // 8 B
typedef __attribute__((ext_vector_type(8))) short short8;         // bf16x8 MFMA frag
typedef __attribute__((ext_vector_type(4))) float f32x4;          // MFMA acc

typedef __attribute__((address_space(1))) const void GV;
typedef __attribute__((address_space(3))) void LV;
__device__ __forceinline__ void gl16(const void* g, void* l) {
    __builtin_amdgcn_global_load_lds((GV*)g, (LV*)l, 16, 0, 0);
}

__device__ __forceinline__ float b2f(unsigned short u) {
    unsigned int v = ((unsigned int)u) << 16; float f; __builtin_memcpy(&f, &v, 4); return f;
}
__device__ __forceinline__ unsigned short f2b(float x) {
    unsigned int u; __builtin_memcpy(&u, &x, 4);
    u = (u + 0x7FFFu + ((u >> 16) & 1u)) >> 16;   // RNE
    return (unsigned short)u;
}
__device__ __forceinline__ void cvt8(const float* __restrict__ g, unsigned short* o) {
    vf4 a = *(const vf4*)g, b = *(const vf4*)(g + 4);
    o[0] = f2b(a[0]); o[1] = f2b(a[1]); o[2] = f2b(a[2]); o[3] = f2b(a[3]);
    o[4] = f2b(b[0]); o[5] = f2b(b[1]); o[6] = f2b(b[2]); o[7] = f2b(b[3]);
}
// fast transcendentals: v_rcp_f32-based; correct saturation at +/-inf.
__device__ __forceinline__ float frcp(float x) { return __builtin_amdgcn_rcpf(x); }
__device__ __forceinline__ float sigm(float v) { return frcp(1.f + __expf(-v)); }
__device__ __forceinline__ float ftanh(float v) { return 1.f - 2.f * frcp(__expf(2.f * v) + 1.f); }

// ---------------------------------------------------------------------------
// adjxw: blocks 0..4095 = adj pass (12 loads prefetched up-front, adj->f32
// copy, bit planes, dinv f32+bf16; blocks <864 also convert [wih|whh|fcw]->wb).
// Blocks 4096..4863 = gemm_xw (UNSCALED u = x@gnn_w, transposed store uT).
// ---------------------------------------------------------------------------
__global__ __launch_bounds__(256) void adjxw(const int* __restrict__ adj,
        float* __restrict__ adj_out, unsigned char* __restrict__ abits,
        float* __restrict__ dinv, unsigned short* __restrict__ dinvb,
        const float* __restrict__ wih, const float* __restrict__ whh,
        const float* __restrict__ fcw, unsigned short* __restrict__ wb,
        const float* __restrict__ gnnw, const float* __restrict__ x,
        unsigned short* __restrict__ uT) {
    const int bid = blockIdx.x, t = threadIdx.x;
    __shared__ __align__(16) unsigned short sA[64 * SA], sB[64 * SA];  // xw branch
    __shared__ unsigned char nib[3][1024];                              // adj branch
    __shared__ float r0[256], r1[256], r2[256];
    if (bid >= 4096) {
        // ---------------- fused gemm_xw (unscaled) ----------------
        const int b2 = bid - 4096;
        const int k = b2 >> 8, rem = b2 & 255, bn = rem >> 2, bg = rem & 3;
        const int lane = t & 63, wave = t >> 6;
        const int m = lane & 15, q = lane >> 4, ko = q * 8;
        const int h0 = bg * 64;
        f32x4 acc[4] = {};
        const float* A0 = x + (size_t)(bn * 64) * FD;
        const float* B0 = gnnw + (size_t)k * FD * HD;
        const int r = t >> 2, c8 = (t & 3) << 3;
        const int fB = t >> 3, c8B = (t & 7) << 3;
        for (int k0 = 0; k0 < FD; k0 += 32) {
            alignas(16) unsigned short tA[8], tB[8];
            cvt8(A0 + (size_t)r * FD + k0 + c8, tA);
            *(vu4*)(sA + r * SA + c8) = *(vu4*)tA;
            cvt8(B0 + (size_t)(k0 + fB) * HD + h0 + c8B, tB);
#pragma unroll
            for (int e = 0; e < 8; ++e) sB[(c8B + e) * SA + fB] = tB[e];
            __syncthreads();
            short8 af = *(const short8*)(sA + (wave * 16 + m) * SA + ko);
#pragma unroll
            for (int ct = 0; ct < 4; ++ct) {
                short8 bf = *(const short8*)(sB + (ct * 16 + m) * SA + ko);
                acc[ct] = __builtin_amdgcn_mfma_f32_16x16x32_bf16(af, bf, acc[ct], 0, 0, 0);
            }
            __syncthreads();
        }
        unsigned short* uTk = uT + (size_t)k * HD * NN_;
#pragma unroll
        for (int ct = 0; ct < 4; ++ct)
#pragma unroll
            for (int r2 = 0; r2 < 4; ++r2) {
                int col = h0 + ct * 16 + m;
                int row = bn * 64 + wave * 16 + q * 4 + r2;
                uTk[(size_t)col * NN_ + row] = f2b(acc[ct][r2]);
            }
        return;
    }
    // ---------------- adj pass ----------------
    const int i = bid;
    if (i < 864) {   // one-time weight conversion: wih|whh|fcw (exactly 864*2048)
        size_t e = ((size_t)i * 256 + t) * 8;
        const float* src; size_t off;
        if (e < 786432)       { src = wih; off = e; }
        else if (e < 1572864) { src = whh; off = e - 786432; }
        else                  { src = fcw; off = e - 1572864; }
        alignas(16) unsigned short o[8];
        cvt8(src + off, o);
        *(vu4*)(wb + e) = *(vu4*)o;
    }
    const int* src = adj + (size_t)i * 12288;
    float* dstf = adj_out + (size_t)i * 12288;
    // Prefetch ALL 12 loads up-front: 12 independent 16B loads in flight.
    vi4 va[12];
#pragma unroll
    for (int it = 0; it < 4; ++it) {
        int jq = (it * 256 + t) * 4;
        va[it * 3 + 0] = *(const vi4*)(src + jq * 3);
        va[it * 3 + 1] = *(const vi4*)(src + jq * 3 + 4);
        va[it * 3 + 2] = *(const vi4*)(src + jq * 3 + 8);
    }
    float s0 = 0.f, s1 = 0.f, s2 = 0.f;
#pragma unroll
    for (int it = 0; it < 4; ++it) {
        int p = it * 256 + t;
        int jq = p * 4;
        vi4 a = va[it * 3 + 0];
        vi4 b = va[it * 3 + 1];
        vi4 c = va[it * 3 + 2];
        int vv[12] = {a[0],a[1],a[2],a[3],b[0],b[1],b[2],b[3],c[0],c[1],c[2],c[3]};
        float ff[12];
#pragma unroll
        for (int e = 0; e < 12; ++e) ff[e] = vv[e] ? 1.f : 0.f;
        vf4 w0 = {ff[0],ff[1],ff[2],ff[3]}, w1 = {ff[4],ff[5],ff[6],ff[7]}, w2 = {ff[8],ff[9],ff[10],ff[11]};
        *(vf4*)(dstf + jq * 3) = w0; *(vf4*)(dstf + jq * 3 + 4) = w1; *(vf4*)(dstf + jq * 3 + 8) = w2;
#pragma unroll
        for (int k = 0; k < 3; ++k) {
            unsigned int nb = (vv[k] ? 1u : 0u) | (vv[3 + k] ? 2u : 0u)
                            | (vv[6 + k] ? 4u : 0u) | (vv[9 + k] ? 8u : 0u);
            nib[k][p] = (unsigned char)nb;
        }
        s0 += ff[0] + ff[3] + ff[6] + ff[9];
        s1 += ff[1] + ff[4] + ff[7] + ff[10];
        s2 += ff[2] + ff[5] + ff[8] + ff[11];
    }
    r0[t] = s0; r1[t] = s1; r2[t] = s2;
    __syncthreads();
#pragma unroll
    for (int k = 0; k < 3; ++k) {
        unsigned int b0 = (unsigned int)nib[k][t * 4 + 0] | ((unsigned int)nib[k][t * 4 + 1] << 4);
        unsigned int b1 = (unsigned int)nib[k][t * 4 + 2] | ((unsigned int)nib[k][t * 4 + 3] << 4);
        *(unsigned short*)(abits + ((size_t)k * NN_ + i) * 512 + t * 2) =
            (unsigned short)(b0 | (b1 << 8));
    }
    for (int off = 128; off > 0; off >>= 1) {
        if (t < off) { r0[t] += r0[t + off]; r1[t] += r1[t + off]; r2[t] += r2[t + off]; }
        __syncthreads();
    }
    if (t == 0) {
        float d0 = 1.f / sqrtf(1.f + r0[0]);
        float d1 = 1.f / sqrtf(1.f + r1[0]);
        float d2 = 1.f / sqrtf(1.f + r2[0]);
        dinv[i]           = d0; dinvb[i]            = f2b(d0);
        dinv[NN_ + i]     = d1; dinvb[NN_ + i]      = f2b(d1);
        dinv[2 * NN_ + i] = d2; dinvb[2 * NN_ + i]  = f2b(d2);
    }
}

// ---------------------------------------------------------------------------
// gemm_agg v7: 128x128 tiles, 2x2 waves, j-split s=4 (grid 768, XCD swizzle).
// K-step 64 via two 32-j half-buffers (sB0/sB1, 64B pitch each) -> one
// barrier pair per 32 MFMA. A expanded from bit-plane to bf16(dinv_j).
// ---------------------------------------------------------------------------
__global__ __launch_bounds__(256) void gemm_agg(const unsigned char* __restrict__ abits,
        const unsigned short* __restrict__ uT, const unsigned short* __restrict__ dinvb,
        const float* __restrict__ dinv, unsigned short* __restrict__ pbuf) {
    __shared__ __align__(16) unsigned char bitsA[128 * BPITCH];    // 18 KB
    __shared__ __align__(16) unsigned short sB0[128 * 32];          // 8 KB (j half 0)
    __shared__ __align__(16) unsigned short sB1[128 * 32];          // 8 KB (j half 1)
    __shared__ __align__(16) unsigned short sDv[1024];              // 2 KB dinv slice
    const int d = blockIdx.x;                  // 0..767
    const int w = (d & 7) * 96 + (d >> 3);     // bijective XCD-chunked remap
    const int bh = w & 1, bi = (w >> 1) & 31, z = w >> 6;
    const int k = z >> 2, s = z & 3;
    const int t = threadIdx.x, lane = t & 63, wave = t >> 6;
    const int wi = wave & 1, wh = wave >> 1;
    const int m = lane & 15, q = lane >> 4, ko = q * 8;
    const int i0 = bi * 128, h0 = bh * 128, jbase = s * 1024;
    {   // stage the A bit-tile once: 128 rows x 128 B
        const int row = t >> 1, half = t & 1;
        const unsigned char* bsrc = abits + ((size_t)k * NN_ + i0 + row) * 512 + s * 128 + half * 64;
        unsigned char* bdst = bitsA + row * BPITCH + half * 64;
        vu4 v0 = *(const vu4*)(bsrc);
        vu4 v1 = *(const vu4*)(bsrc + 16);
        vu4 v2 = *(const vu4*)(bsrc + 32);
        vu4 v3 = *(const vu4*)(bsrc + 48);
        *(vu4*)(bdst)      = v0;
        *(vu4*)(bdst + 16) = v1;
        *(vu4*)(bdst + 32) = v2;
        *(vu4*)(bdst + 48) = v3;
    }
    if (t < 128)   // stage the dinv_j slice for this j-chunk (1024 bf16)
        *(vu4*)(sDv + t * 8) = *(const vu4*)(dinvb + (size_t)k * NN_ + jbase + t * 8);
    f32x4 acc[4][4] = {};
    const int lrow = lane >> 2, lcol = (lane & 3) << 3;
    const unsigned short* Bg0 = uT + ((size_t)(k * 256 + h0 + wave * 32 + lrow)) * NN_ + jbase + lcol;
    const unsigned short* Bg1 = Bg0 + (size_t)16 * NN_;
    unsigned short* lB00 = sB0 + (wave * 32) * 32;
    unsigned short* lB01 = lB00 + 16 * 32;
    unsigned short* lB10 = sB1 + (wave * 32) * 32;
    unsigned short* lB11 = lB10 + 16 * 32;
    const int arowb = (wi * 64 + m) * BPITCH + q;
    for (int j0 = 0; j0 < 1024; j0 += 64) {
        gl16(Bg0 + j0, lB00);
        gl16(Bg1 + j0, lB01);
        gl16(Bg0 + j0 + 32, lB10);
        gl16(Bg1 + j0 + 32, lB11);
        __syncthreads();
        const int jby = j0 >> 3;
        short8 dv0 = *(const short8*)(sDv + j0 + ko);
        short8 dv1 = *(const short8*)(sDv + j0 + 32 + ko);
        short8 af0[4], af1[4];
#pragma unroll
        for (int rt = 0; rt < 4; ++rt) {
            unsigned int by0 = bitsA[arowb + rt * 16 * BPITCH + jby];
            unsigned int by1 = bitsA[arowb + rt * 16 * BPITCH + jby + 4];
#pragma unroll
            for (int e = 0; e < 8; ++e) {
                af0[rt][e] = (short)(((by0 >> e) & 1u) ? dv0[e] : (short)0);
                af1[rt][e] = (short)(((by1 >> e) & 1u) ? dv1[e] : (short)0);
            }
        }
#pragma unroll
        for (int ct = 0; ct < 4; ++ct) {
            short8 bf0 = *(const short8*)(sB0 + (wh * 64 + ct * 16 + m) * 32 + ko);
#pragma unroll
            for (int rt = 0; rt < 4; ++rt)
                acc[rt][ct] = __builtin_amdgcn_mfma_f32_16x16x32_bf16(af0[rt], bf0, acc[rt][ct], 0, 0, 0);
        }
#pragma unroll
        for (int ct = 0; ct < 4; ++ct) {
            short8 bf1 = *(const short8*)(sB1 + (wh * 64 + ct * 16 + m) * 32 + ko);
#pragma unroll
            for (int rt = 0; rt < 4; ++rt)
                acc[rt][ct] = __builtin_amdgcn_mfma_f32_16x16x32_bf16(af1[rt], bf1, acc[rt][ct], 0, 0, 0);
        }
        __syncthreads();
    }
    const int addself = ((bi >> 3) == s);
#pragma unroll
    for (int rt = 0; rt < 4; ++rt)
#pragma unroll
        for (int ct = 0; ct < 4; ++ct)
#pragma unroll
            for (int r2 = 0; r2 < 4; ++r2) {
                int row = i0 + wi * 64 + rt * 16 + q * 4 + r2;
                int col = h0 + wh * 64 + ct * 16 + m;
                float v = acc[rt][ct][r2];
                if (addself)
                    v += dinv[(size_t)k * NN_ + row]
                       * b2f(uT[((size_t)k * 256 + col) * NN_ + row]);
                pbuf[(((size_t)s * 3 + k) * NN_ + row) * 256 + col] = f2b(v);
            }
}

// ---------------------------------------------------------------------------
// agg_reduce: xt[k][i][h] = f2b(dinv[k][i] * (sum_s pbuf[s]) + gnnb[k][h])
// ---------------------------------------------------------------------------
__global__ __launch_bounds__(256) void agg_reduce(const unsigned short* __restrict__ pbuf,
        const float* __restrict__ dinv, const float* __restrict__ gnnb,
        unsigned short* __restrict__ xt) {
    size_t e8 = ((size_t)blockIdx.x * 256 + threadIdx.x) * 8;
    int k = (int)(e8 >> 20);
    int i = (int)((e8 >> 8) & 4095);
    int h = (int)(e8 & 255);
    float di = dinv[k * NN_ + i];
    const size_t KIH = (size_t)KC * NN_ * HD;
    alignas(16) unsigned short p0[8], p1[8], p2[8], p3[8], o[8];
    *(vu4*)p0 = *(const vu4*)(pbuf + 0 * KIH + e8);
    *(vu4*)p1 = *(const vu4*)(pbuf + 1 * KIH + e8);
    *(vu4*)p2 = *(const vu4*)(pbuf + 2 * KIH + e8);
    *(vu4*)p3 = *(const vu4*)(pbuf + 3 * KIH + e8);
#pragma unroll
    for (int e = 0; e < 8; ++e) {
        float v = b2f(p0[e]) + b2f(p1[e]) + b2f(p2[e]) + b2f(p3[e]);
        o[e] = f2b(di * v + gnnb[k * HD + h + e]);
    }
    *(vu4*)(xt + e8) = *(vu4*)o;
}

// ---------------------------------------------------------------------------
// lstm_gate (t=0): NT GEMM xt @ wih^T via gl16 (K-step 64, half-buffers);
// +bih+bhh -> gX2; fused t=0 cell. Grid 768, XCD swizzle.
// ---------------------------------------------------------------------------
__global__ __launch_bounds__(256) void lstm_gate(const unsigned short* __restrict__ A,
        const unsigned short* __restrict__ W, const float* __restrict__ b1,
        const float* __restrict__ b2, unsigned short* __restrict__ gX2,
        float* __restrict__ cbuf, unsigned short* __restrict__ hbuf) {
    __shared__ __align__(16) unsigned short sA0[128 * 32], sA1[128 * 32];   // 16 KB
    __shared__ __align__(16) unsigned short sB0[128 * 32], sB1[128 * 32];   // 16 KB
    const int d = blockIdx.x;
    const int w = (d & 7) * 96 + (d >> 3);
    const int chb = w & 7, bn = w >> 3;
    const int t = threadIdx.x, lane = t & 63, wave = t >> 6;
    const int m = lane & 15, q = lane >> 4, ko = q * 8;
    const int kk = bn >> 5;
    f32x4 acc[2][2][4] = {};
    const int lrow = lane >> 2, lcol = (lane & 3) << 3;
    const unsigned short* A0 = A + (size_t)bn * 128 * 256;
    const unsigned short* W0 = W + (size_t)kk * GD * 256 + (size_t)chb * 32 * 256;
    const unsigned short* Ag0 = A0 + (size_t)(wave * 32 + lrow) * 256 + lcol;
    const unsigned short* Ag1 = Ag0 + 16 * 256;
    const unsigned short* Bg0 = W0 + (size_t)(wave * 256 + lrow) * 256 + lcol;
    const unsigned short* Bg1 = Bg0 + 16 * 256;
    unsigned short* lA00 = sA0 + (wave * 32) * 32; unsigned short* lA01 = lA00 + 16 * 32;
    unsigned short* lA10 = sA1 + (wave * 32) * 32; unsigned short* lA11 = lA10 + 16 * 32;
    unsigned short* lB00 = sB0 + (wave * 32) * 32; unsigned short* lB01 = lB00 + 16 * 32;
    unsigned short* lB10 = sB1 + (wave * 32) * 32; unsigned short* lB11 = lB10 + 16 * 32;
    for (int k0 = 0; k0 < 256; k0 += 64) {
        gl16(Ag0 + k0, lA00);      gl16(Ag1 + k0, lA01);
        gl16(Ag0 + k0 + 32, lA10); gl16(Ag1 + k0 + 32, lA11);
        gl16(Bg0 + k0, lB00);      gl16(Bg1 + k0, lB01);
        gl16(Bg0 + k0 + 32, lB10); gl16(Bg1 + k0 + 32, lB11);
        __syncthreads();
        short8 af0[2], af1[2];
#pragma unroll
        for (int rt = 0; rt < 2; ++rt) {
            af0[rt] = *(const short8*)(sA0 + (wave * 32 + rt * 16 + m) * 32 + ko);
            af1[rt] = *(const short8*)(sA1 + (wave * 32 + rt * 16 + m) * 32 + ko);
        }
#pragma unroll
        for (int g = 0; g < 4; ++g)
#pragma unroll
            for (int cc = 0; cc < 2; ++cc) {
                short8 bf0 = *(const short8*)(sB0 + (g * 32 + cc * 16 + m) * 32 + ko);
#pragma unroll
                for (int rt = 0; rt < 2; ++rt)
                    acc[rt][cc][g] = __builtin_amdgcn_mfma_f32_16x16x32_bf16(af0[rt], bf0, acc[rt][cc][g], 0, 0, 0);
                short8 bf1 = *(const short8*)(sB1 + (g * 32 + cc * 16 + m) * 32 + ko);
#pragma unroll
                for (int rt = 0; rt < 2; ++rt)
                    acc[rt][cc][g] = __builtin_amdgcn_mfma_f32_16x16x32_bf16(af1[rt], bf1, acc[rt][cc][g], 0, 0, 0);
            }
        __syncthreads();
    }
#pragma unroll
    for (int rt = 0; rt < 2; ++rt)
#pragma unroll
        for (int cc = 0; cc < 2; ++cc)
#pragma unroll
            for (int r2 = 0; r2 < 4; ++r2) {
                int row = bn * 128 + wave * 32 + rt * 16 + q * 4 + r2;
                int ch = chb * 32 + cc * 16 + m;
                size_t goff = ((size_t)row * 256 + ch) * 4;
                size_t coff = (size_t)row * 256 + ch;
                float v[4];
                vus4 o;
#pragma unroll
                for (int g = 0; g < 4; ++g) {
                    v[g] = acc[rt][cc][g][r2]
                         + b1[kk * GD + g * 256 + ch] + b2[kk * GD + g * 256 + ch];
                    o[g] = f2b(v[g]);
                }
                *(vus4*)(gX2 + goff) = o;
                float cn = sigm(v[0]) * ftanh(v[2]);
                cbuf[coff] = cn;
                hbuf[coff] = f2b(sigm(v[3]) * ftanh(cn));
            }
}

// ---------------------------------------------------------------------------
// lstm_step: NT GEMM h_prev @ whh^T (K-step 64, half-buffers); g = v + gX2;
// cell update with cbuf (f32); write c, h_next (ping-pong, no race).
// ---------------------------------------------------------------------------
__global__ __launch_bounds__(256) void lstm_step(const unsigned short* __restrict__ A,
        const unsigned short* __restrict__ W, const unsigned short* __restrict__ gX2,
        float* __restrict__ cbuf, unsigned short* __restrict__ hbuf) {
    __shared__ __align__(16) unsigned short sA0[128 * 32], sA1[128 * 32];   // 16 KB
    __shared__ __align__(16) unsigned short sB0[128 * 32], sB1[128 * 32];   // 16 KB
    const int d = blockIdx.x;
    const int w = (d & 7) * 96 + (d >> 3);
    const int chb = w & 7, bn = w >> 3;
    const int t = threadIdx.x, lane = t & 63, wave = t >> 6;
    const int m = lane & 15, q = lane >> 4, ko = q * 8;
    const int kk = bn >> 5;
    f32x4 acc[2][2][4] = {};
    const int lrow = lane >> 2, lcol = (lane & 3) << 3;
    const unsigned short* A0 = A + (size_t)bn * 128 * 256;
    const unsigned short* W0 = W + (size_t)kk * GD * 256 + (size_t)chb * 32 * 256;
    const unsigned short* Ag0 = A0 + (size_t)(wave * 32 + lrow) * 256 + lcol;
    const unsigned short* Ag1 = Ag0 + 16 * 256;
    const unsigned short* Bg0 = W0 + (size_t)(wave * 256 + lrow) * 256 + lcol;
    const unsigned short* Bg1 = Bg0 + 16 * 256;
    unsigned short* lA00 = sA0 + (wave * 32) * 32; unsigned short* lA01 = lA00 + 16 * 32;
    unsigned short* lA10 = sA1 + (wave * 32) * 32; unsigned short* lA11 = lA10 + 16 * 32;
    unsigned short* lB00 = sB0 + (wave * 32) * 32; unsigned short* lB01 = lB00 + 16 * 32;
    unsigned short* lB10 = sB1 + (wave * 32) * 32; unsigned short* lB11 = lB10 + 16 * 32;
    for (int k0 = 0; k0 < 256; k0 += 64) {
        gl16(Ag0 + k0, lA00);      gl16(Ag1 + k0, lA01);
        gl16(Ag0 + k0 + 32, lA10); gl16(Ag1 + k0 + 32, lA11);
        gl16(Bg0 + k0, lB00);      gl16(Bg1 + k0, lB01);
        gl16(Bg0 + k0 + 32, lB10); gl16(Bg1 + k0 + 32, lB11);
        __syncthreads();
        short8 af0[2], af1[2];
#pragma unroll
        for (int rt = 0; rt < 2; ++rt) {
            af0[rt] = *(const short8*)(sA0 + (wave * 32 + rt * 16 + m) * 32 + ko);
            af1[rt] = *(const short8*)(sA1 + (wave * 32 + rt * 16 + m) * 32 + ko);
        }
#pragma unroll
        for (int g = 0; g < 4; ++g)
#pragma unroll
            for (int cc = 0; cc < 2; ++cc) {
                short8 bf0 = *(const short8*)(sB0 + (g * 32 + cc * 16 + m) * 32 + ko);
#pragma unroll
                for (int rt = 0; rt < 2; ++rt)
                    acc[rt][cc][g] = __builtin_amdgcn_mfma_f32_16x16x32_bf16(af0[rt], bf0, acc[rt][cc][g], 0, 0, 0);
                short8 bf1 = *(const short8*)(sB1 + (g * 32 + cc * 16 + m) * 32 + ko);
#pragma unroll
                for (int rt = 0; rt < 2; ++rt)
                    acc[rt][cc][g] = __builtin_amdgcn_mfma_f32_16x16x32_bf16(af1[rt], bf1, acc[rt][cc][g], 0, 0, 0);
            }
        __syncthreads();
    }
#pragma unroll
    for (int rt = 0; rt < 2; ++rt)
#pragma unroll
        for (int cc = 0; cc < 2; ++cc)
#pragma unroll
            for (int r2 = 0; r2 < 4; ++r2) {
                int row = bn * 128 + wave * 32 + rt * 16 + q * 4 + r2;
                int ch = chb * 32 + cc * 16 + m;
                size_t goff = ((size_t)row * 256 + ch) * 4;
                size_t coff = (size_t)row * 256 + ch;
                vus4 gv = *(const vus4*)(gX2 + goff);
                float iv = acc[rt][cc][0][r2] + b2f(gv[0]);
                float fv = acc[rt][cc][1][r2] + b2f(gv[1]);
                float gg = acc[rt][cc][2][r2] + b2f(gv[2]);
                float ov = acc[rt][cc][3][r2] + b2f(gv[3]);
                float cn = sigm(fv) * cbuf[coff] + sigm(iv) * ftanh(gg);
                cbuf[coff] = cn;
                hbuf[coff] = f2b(sigm(ov) * ftanh(cn));
            }
}

// ---------------------------------------------------------------------------
// fc_final: one block computes 64x64 output for ALL 3 k (acc[3][4]), then the
// final epilogue inline: delta_k = tanh(h@fcw^T + fcb); pred/res from x+delta.
// ---------------------------------------------------------------------------
__global__ __launch_bounds__(256) void fc_final(const unsigned short* __restrict__ A,
        const unsigned short* __restrict__ W, const float* __restrict__ fcb,
        const float* __restrict__ x, float* __restrict__ pred, float* __restrict__ res) {
    __shared__ __align__(16) unsigned short sA[3][64 * 32], sB[3][64 * 32];  // 24 KB
    const int bg = blockIdx.x, bn = blockIdx.y;
    const int t = threadIdx.x, lane = t & 63, wave = t >> 6;
    const int m = lane & 15, q = lane >> 4, ko = q * 8;
    f32x4 acc[3][4] = {};
    const int lrow = lane >> 2, lcol = (lane & 3) << 3;
    const unsigned short* Ag[3]; const unsigned short* Bg[3];
#pragma unroll
    for (int k = 0; k < 3; ++k) {
        Ag[k] = A + ((size_t)k * NN_ + bn * 64 + wave * 16 + lrow) * HD + lcol;
        Bg[k] = W + ((size_t)k * FD + bg * 64 + wave * 16 + lrow) * HD + lcol;
    }
    for (int k0 = 0; k0 < HD; k0 += 32) {
#pragma unroll
        for (int k = 0; k < 3; ++k) {
            gl16(Ag[k] + k0, sA[k] + (wave * 16) * 32);
            gl16(Bg[k] + k0, sB[k] + (wave * 16) * 32);
        }
        __syncthreads();
#pragma unroll
        for (int k = 0; k < 3; ++k) {
            short8 af = *(const short8*)(sA[k] + (wave * 16 + m) * 32 + ko);
#pragma unroll
            for (int ct = 0; ct < 4; ++ct) {
                short8 bf = *(const short8*)(sB[k] + (ct * 16 + m) * 32 + ko);
                acc[k][ct] = __builtin_amdgcn_mfma_f32_16x16x32_bf16(af, bf, acc[k][ct], 0, 0, 0);
            }
        }
        __syncthreads();
    }
#pragma unroll
    for (int ct = 0; ct < 4; ++ct)
#pragma unroll
        for (int r2 = 0; r2 < 4; ++r2) {
            int col = bg * 64 + ct * 16 + m;
            int row = bn * 64 + wave * 16 + q * 4 + r2;
            float d0 = ftanh(acc[0][ct][r2] + fcb[col]);
            float d1 = ftanh(acc[1][ct][r2] + fcb[FD + col]);
            float d2 = ftanh(acc[2][ct][r2] + fcb[2 * FD + col]);
            float xf = x[(size_t)row * FD + col];
            bool sg = (col >= 10) && (col < 253);
            float dm = (d0 + d1 + d2) * (1.f / 3.f);
            float p = xf + dm; if (sg) p = sigm(p);
            pred[(size_t)row * FD + col] = p;
            float z0 = xf + d0; if (sg) z0 = sigm(z0);
            float z1 = xf + d1; if (sg) z1 = sigm(z1);
            float z2 = xf + d2; if (sg) z2 = sigm(z2);
            size_t rb = ((size_t)row * FD + col) * 3;
            res[rb] = z0; res[rb + 1] = z1; res[rb + 2] = z2;
        }
}

extern "C" void kernel_launch(void* const* d_in, const int* in_sizes, int n_in,
                              void* d_out, int out_size, void* d_ws, size_t ws_size,
                              hipStream_t stream) {
    const float* x    = (const float*)d_in[0];
    const float* gnnw = (const float*)d_in[1];
    const float* gnnb = (const float*)d_in[2];
    const float* wih  = (const float*)d_in[3];
    const float* whh  = (const float*)d_in[4];
    const float* bih  = (const float*)d_in[5];
    const float* bhh  = (const float*)d_in[6];
    const float* fcw  = (const float*)d_in[7];
    const float* fcb  = (const float*)d_in[8];
    const int*   adj  = (const int*)d_in[9];

    float* out = (float*)d_out;
    float* out_pred = out;
    float* out_res  = out + (size_t)NN_ * FD;
    float* out_adj  = out + (size_t)NN_ * FD * 4;

    // ws layout (~92 MB):
    char* ws = (char*)d_ws;
    float*          dinv  = (float*)ws;                          //        0 (49,152)
    unsigned short* dinvb = (unsigned short*)(ws + 49152);       // bf16 dinv (24,576)
    unsigned short* R1    = (unsigned short*)(ws + 73728);       // uT -> h  (6,291,456)
    unsigned short* H1    = (unsigned short*)(ws + 6365184);     // h pong   (6,291,456)
    unsigned short* XT    = (unsigned short*)(ws + 12656640);    // xt       (6,291,456)
    unsigned short* wb    = (unsigned short*)(ws + 18948096);    // weights  (3,538,944)
    unsigned char*  abits = (unsigned char*)(ws + 22487040);     // bits     (6,291,456)
    unsigned short* pbuf  = (unsigned short*)(ws + 28778496);    // partials (25,165,824)
    unsigned short* gX2   = (unsigned short*)(ws + 53944320);    // Wx gates (25,165,824)
    float*          cbuf  = (float*)(ws + 79110144);             // c f32    (12,582,912)
    const unsigned short* wihb = wb;
    const unsigned short* whhb = wb + 786432;
    const unsigned short* fcwb = wb + 1572864;
    (void)ws_size; (void)in_sizes; (void)n_in; (void)out_size;

    // adj pass + weight cvt + fused UNSCALED gemm_xw (blocks 4096..4863)
    adjxw<<<dim3(4864), 256, 0, stream>>>(adj, out_adj, abits, dinv, dinvb,
                                          wih, whh, fcw, wb, gnnw, x, R1 /*uT*/);
    gemm_agg<<<dim3(768), 256, 0, stream>>>(abits, R1 /*uT*/, dinvb, dinv, pbuf);
    agg_reduce<<<dim3(1536), 256, 0, stream>>>(pbuf, dinv, gnnb, XT);
    // t=0: xt@wih + biases -> gX2; cell0 -> cbuf, h -> R1 (uT dead now)
    lstm_gate<<<dim3(768), 256, 0, stream>>>(XT, wihb, bih, bhh, gX2, cbuf, R1);
    // steps 1..4, ping-pong R1 <-> H1 (h_last lands in R1)
    lstm_step<<<dim3(768), 256, 0, stream>>>(R1, whhb, gX2, cbuf, H1);
    lstm_step<<<dim3(768), 256, 0, stream>>>(H1, whhb, gX2, cbuf, R1);
    lstm_step<<<dim3(768), 256, 0, stream>>>(R1, whhb, gX2, cbuf, H1);
    lstm_step<<<dim3(768), 256, 0, stream>>>(H1, whhb, gX2, cbuf, R1);
    fc_final<<<dim3(4, 64), 256, 0, stream>>>(R1, fcwb, fcb, x, out_pred, out_res);
}